// Round 6
// baseline (922.914 us; speedup 1.0000x reference)
//
#include <hip/hip_runtime.h>
#include <hip/hip_bf16.h>
#include <math.h>

#define D_MODEL 1024
#define D_STATE 16
#define D_CONV  4
#define D_INNER 2048
#define TLEN    1024
#define BATCH   2
#define NTOK    (BATCH*TLEN)   // 2048

typedef __attribute__((ext_vector_type(8))) short bf16x8;
typedef __attribute__((ext_vector_type(4))) float f32x4;

__device__ __forceinline__ float silu_f(float v) { return v / (1.f + __expf(-v)); }

// fp32 -> bf16 (RNE), finite inputs
__device__ __forceinline__ short f2bf(float x) {
    unsigned u = __builtin_bit_cast(unsigned, x);
    unsigned r = (u + 0x7FFFu + ((u >> 16) & 1u)) >> 16;
    return (short)r;
}

// ---------------- RMSNorm: one block per token, 256 thr, float4 ----------------
__global__ __launch_bounds__(256) void rmsnorm_kernel(const float* __restrict__ x,
                                                      const float* __restrict__ g,
                                                      float* __restrict__ xn) {
    int row = blockIdx.x;
    int tid = threadIdx.x;
    const float4* xr = (const float4*)(x + (size_t)row * D_MODEL);
    float4 v = xr[tid];
    float ss = v.x*v.x + v.y*v.y + v.z*v.z + v.w*v.w;
    #pragma unroll
    for (int off = 32; off; off >>= 1) ss += __shfl_down(ss, off);
    __shared__ float red[4];
    if ((tid & 63) == 0) red[tid >> 6] = ss;
    __syncthreads();
    float tot = red[0] + red[1] + red[2] + red[3];
    float scale = rsqrtf(tot * (1.f / D_MODEL) + 1e-6f);
    float4 gv = ((const float4*)g)[tid];
    float4 o;
    o.x = v.x * scale * gv.x;
    o.y = v.y * scale * gv.y;
    o.z = v.z * scale * gv.z;
    o.w = v.w * scale * gv.w;
    ((float4*)(xn + (size_t)row * D_MODEL))[tid] = o;
}

// ---------- bf16-MFMA NT GEMM: C[m][n] = sum_k A[m][k]*B[n][k] (+resid) ----------
// BM=128, BN in {128,64}, BK=32. 256 threads = 4 waves (2x2). Each wave:
// 4 x NJ grid of 16x16x32 mfma tiles. fp32 inputs converted to bf16 (RNE)
// during LDS staging. LDS rows padded to 40 shorts (80 B): fragment
// ds_read_b128 is 2-way bank-aliased (free, m136).
// Fragment maps (guide §3, m89-verified): A/B lane: row/col = lane&15,
// k = (lane>>4)*8 + i (contiguous bf16x8). C/D: col = lane&15,
// row = (lane>>4)*4 + reg.
template <int BN, int RESID>
__global__ __launch_bounds__(256) void gemm_bf16_nt(const float* __restrict__ A,
                                                    const float* __restrict__ B,
                                                    const float* __restrict__ resid,
                                                    float* __restrict__ C,
                                                    int M, int N, int K) {
    constexpr int BM = 128;
    constexpr int WN = BN / 2;
    constexpr int NJ = WN / 16;
    __shared__ short Asm[BM][40];
    __shared__ short Bsm[BN][40];
    int tid = threadIdx.x;
    int lane = tid & 63, w = tid >> 6;
    int wr = w >> 1, wc = w & 1;
    int bm = blockIdx.y * BM, bn = blockIdx.x * BN;
    int lrow = lane & 15, kg = (lane >> 4) * 8;
    f32x4 acc[4][NJ];
    #pragma unroll
    for (int i = 0; i < 4; i++)
        #pragma unroll
        for (int j = 0; j < NJ; j++)
            acc[i][j] = (f32x4){0.f, 0.f, 0.f, 0.f};

    for (int k0 = 0; k0 < K; k0 += 32) {
        // ---- stage A (BM x 32) ----
        #pragma unroll
        for (int c = tid; c < BM * 4; c += 256) {
            int row = c >> 2, ch = c & 3;
            const float* p = A + (size_t)(bm + row) * K + k0 + ch * 8;
            float4 v0 = *(const float4*)p;
            float4 v1 = *(const float4*)(p + 4);
            bf16x8 pk;
            pk[0] = f2bf(v0.x); pk[1] = f2bf(v0.y); pk[2] = f2bf(v0.z); pk[3] = f2bf(v0.w);
            pk[4] = f2bf(v1.x); pk[5] = f2bf(v1.y); pk[6] = f2bf(v1.z); pk[7] = f2bf(v1.w);
            *(bf16x8*)&Asm[row][ch * 8] = pk;
        }
        // ---- stage B (BN x 32) ----
        #pragma unroll
        for (int c = tid; c < BN * 4; c += 256) {
            int row = c >> 2, ch = c & 3;
            const float* p = B + (size_t)(bn + row) * K + k0 + ch * 8;
            float4 v0 = *(const float4*)p;
            float4 v1 = *(const float4*)(p + 4);
            bf16x8 pk;
            pk[0] = f2bf(v0.x); pk[1] = f2bf(v0.y); pk[2] = f2bf(v0.z); pk[3] = f2bf(v0.w);
            pk[4] = f2bf(v1.x); pk[5] = f2bf(v1.y); pk[6] = f2bf(v1.z); pk[7] = f2bf(v1.w);
            *(bf16x8*)&Bsm[row][ch * 8] = pk;
        }
        __syncthreads();
        bf16x8 aF[4], bF[NJ];
        #pragma unroll
        for (int i = 0; i < 4; i++)
            aF[i] = *(bf16x8*)&Asm[wr * 64 + i * 16 + lrow][kg];
        #pragma unroll
        for (int j = 0; j < NJ; j++)
            bF[j] = *(bf16x8*)&Bsm[wc * WN + j * 16 + lrow][kg];
        #pragma unroll
        for (int i = 0; i < 4; i++)
            #pragma unroll
            for (int j = 0; j < NJ; j++)
                acc[i][j] = __builtin_amdgcn_mfma_f32_16x16x32_bf16(aF[i], bF[j], acc[i][j], 0, 0, 0);
        __syncthreads();
    }
    // ---- epilogue ----
    #pragma unroll
    for (int i = 0; i < 4; i++)
        #pragma unroll
        for (int j = 0; j < NJ; j++)
            #pragma unroll
            for (int r = 0; r < 4; r++) {
                int m = bm + wr * 64 + i * 16 + (lane >> 4) * 4 + r;
                int n = bn + wc * WN + j * 16 + lrow;
                size_t off = (size_t)m * N + n;
                float v = acc[i][j][r];
                if (RESID) v += resid[off];
                C[off] = v;
            }
}

// ---------------- depthwise causal conv (K=4) + SiLU ----------------
__global__ __launch_bounds__(256) void conv_silu_kernel(const float* __restrict__ xz,
                                                        const float* __restrict__ cw,
                                                        const float* __restrict__ cb,
                                                        float* __restrict__ xc) {
    int idx = blockIdx.x * 256 + threadIdx.x;           // over NTOK*D_INNER
    int d  = idx & (D_INNER - 1);
    int bt = idx >> 11;                                  // b*TLEN + t
    int t  = bt & (TLEN - 1);
    float s = cb[d];
    #pragma unroll
    for (int j = 0; j < 4; j++) {
        int tt = t - 3 + j;
        if (tt >= 0)
            s += cw[d * 4 + j] * xz[(size_t)(bt - 3 + j) * (2 * D_INNER) + d];
    }
    xc[idx] = silu_f(s);
}

// ------------- params = xc @ W_x^T  (N=33), one block per token -------------
__global__ __launch_bounds__(256) void params_kernel(const float* __restrict__ xc,
                                                     const float* __restrict__ Wx,
                                                     float* __restrict__ params) {
    int token = blockIdx.x;
    int tid = threadIdx.x;
    const float4* xr = (const float4*)(xc + (size_t)token * D_INNER);
    float4 v0 = xr[tid * 2], v1 = xr[tid * 2 + 1];
    float v[8] = {v0.x, v0.y, v0.z, v0.w, v1.x, v1.y, v1.z, v1.w};
    float acc[33];
    #pragma unroll
    for (int n = 0; n < 33; n++) {
        const float* wr = Wx + (size_t)n * D_INNER + tid * 8;
        float4 w0 = *(const float4*)wr;
        float4 w1 = *(const float4*)(wr + 4);
        acc[n] = v[0]*w0.x + v[1]*w0.y + v[2]*w0.z + v[3]*w0.w
               + v[4]*w1.x + v[5]*w1.y + v[6]*w1.z + v[7]*w1.w;
    }
    __shared__ float red[4][33];
    #pragma unroll
    for (int n = 0; n < 33; n++) {
        float s = acc[n];
        s += __shfl_down(s, 32); s += __shfl_down(s, 16); s += __shfl_down(s, 8);
        s += __shfl_down(s, 4);  s += __shfl_down(s, 2);  s += __shfl_down(s, 1);
        if ((tid & 63) == 0) red[tid >> 6][n] = s;
    }
    __syncthreads();
    if (tid < 33)
        params[(size_t)token * 33 + tid] = red[0][tid] + red[1][tid] + red[2][tid] + red[3][tid];
}

// ---------------- selective scan: thread per (b,d,s) ----------------
// 16 state-lanes per channel; y via __shfl_xor over the 16-lane group.
// Software-pipelined: t+1 loads issue before t's dependent-exp chain.
__global__ __launch_bounds__(256) void scan_kernel(const float* __restrict__ params,
                                                   const float* __restrict__ xc,
                                                   const float* __restrict__ xz,
                                                   const float* __restrict__ Wdt,
                                                   const float* __restrict__ bdt,
                                                   const float* __restrict__ Alog,
                                                   const float* __restrict__ Dp,
                                                   float* __restrict__ yact) {
    int tid = threadIdx.x;
    int s  = tid & 15;
    int ch = blockIdx.x * 16 + (tid >> 4);   // 0..4095, block covers 16 consecutive d
    int b  = ch >> 11;
    int d  = ch & (D_INNER - 1);
    float A    = -__expf(Alog[d * D_STATE + s]);
    float wdt  = Wdt[d];
    float bdtd = bdt[d];
    float Dd   = Dp[d];
    float h = 0.f;
    const float* prow  = params + (size_t)b * TLEN * 33;
    const float* xcrow = xc + (size_t)b * TLEN * D_INNER + d;
    const float* zrow  = xz + (size_t)b * TLEN * (2 * D_INNER) + D_INNER + d;
    float* yrow        = yact + (size_t)b * TLEN * D_INNER + d;

    // prologue loads for t=0
    float Bc  = prow[s];
    float Cc  = prow[16 + s];
    float ldt = prow[32];
    float xcv = xcrow[0];
    float zv  = zrow[0];

    for (int t = 0; t < TLEN; t++) {
        // issue t+1 loads early (independent of h-chain)
        float Bc1 = 0.f, Cc1 = 0.f, ldt1 = 0.f, xcv1 = 0.f, zv1 = 0.f;
        if (t + 1 < TLEN) {
            const float* pn = prow + (size_t)(t + 1) * 33;
            Bc1  = pn[s];
            Cc1  = pn[16 + s];
            ldt1 = pn[32];
            xcv1 = xcrow[(size_t)(t + 1) * D_INNER];
            zv1  = zrow[(size_t)(t + 1) * 2 * D_INNER];   // token stride in xz is 2*D_INNER
        }
        float pre = ldt * wdt + bdtd;
        float dt  = (pre > 20.f) ? pre : log1pf(__expf(pre));
        h = __expf(dt * A) * h + dt * Bc * xcv;
        float y = h * Cc;
        y += __shfl_xor(y, 1); y += __shfl_xor(y, 2);
        y += __shfl_xor(y, 4); y += __shfl_xor(y, 8);
        if (s == 0)
            yrow[(size_t)t * D_INNER] = (y + xcv * Dd) * silu_f(zv);
        Bc = Bc1; Cc = Cc1; ldt = ldt1; xcv = xcv1; zv = zv1;
    }
}

extern "C" void kernel_launch(void* const* d_in, const int* in_sizes, int n_in,
                              void* d_out, int out_size, void* d_ws, size_t ws_size,
                              hipStream_t stream) {
    const float* x      = (const float*)d_in[0];
    const float* g      = (const float*)d_in[1];
    const float* W_in   = (const float*)d_in[2];
    const float* W_out  = (const float*)d_in[3];
    const float* conv_w = (const float*)d_in[4];
    const float* conv_b = (const float*)d_in[5];
    const float* W_x    = (const float*)d_in[6];
    const float* W_dt   = (const float*)d_in[7];
    const float* b_dt   = (const float*)d_in[8];
    const float* A_log  = (const float*)d_in[9];
    const float* Dp     = (const float*)d_in[10];
    float* out = (float*)d_out;

    float* ws   = (float*)d_ws;
    float* xn   = ws;                                   // 2,097,152 f
    float* xz   = xn + (size_t)NTOK * D_MODEL;          // 8,388,608 f
    float* xc   = xz + (size_t)NTOK * 2 * D_INNER;      // 4,194,304 f
    float* par  = xc + (size_t)NTOK * D_INNER;          // 67,584 f
    float* yact = par + (size_t)NTOK * 33;              // 4,194,304 f

    rmsnorm_kernel<<<NTOK, 256, 0, stream>>>(x, g, xn);
    // GEMM1: M=2048, N=4096, K=1024 — bf16 MFMA, 128x128 tiles, 512 blocks
    gemm_bf16_nt<128, 0><<<dim3((2 * D_INNER) / 128, NTOK / 128), 256, 0, stream>>>(
        xn, W_in, nullptr, xz, NTOK, 2 * D_INNER, D_MODEL);
    conv_silu_kernel<<<(NTOK * D_INNER) / 256, 256, 0, stream>>>(xz, conv_w, conv_b, xc);
    params_kernel<<<NTOK, 256, 0, stream>>>(xc, W_x, par);
    scan_kernel<<<(BATCH * D_INNER) / 16, 256, 0, stream>>>(
        par, xc, xz, W_dt, b_dt, A_log, Dp, yact);
    // GEMM2: M=2048, N=1024, K=2048 — bf16 MFMA, 128x64 tiles, 256 blocks
    gemm_bf16_nt<64, 1><<<dim3(D_MODEL / 64, NTOK / 128), 256, 0, stream>>>(
        yact, W_out, x, out, NTOK, D_MODEL, D_INNER);
}

// Round 8
// 792.633 us; speedup vs baseline: 1.1644x; 1.1644x over previous
//
#include <hip/hip_runtime.h>
#include <hip/hip_bf16.h>
#include <math.h>

#define D_MODEL 1024
#define D_STATE 16
#define D_CONV  4
#define D_INNER 2048
#define TLEN    1024
#define BATCH   2
#define NTOK    (BATCH*TLEN)   // 2048

typedef __attribute__((ext_vector_type(8))) short bf16x8;
typedef __attribute__((ext_vector_type(4))) float f32x4;

__device__ __forceinline__ float silu_f(float v) { return v / (1.f + __expf(-v)); }

// fp32 -> bf16 (RNE), finite inputs
__device__ __forceinline__ short f2bf(float x) {
    unsigned u = __builtin_bit_cast(unsigned, x);
    unsigned r = (u + 0x7FFFu + ((u >> 16) & 1u)) >> 16;
    return (short)r;
}

// ---------------- RMSNorm: one block per token, 256 thr, float4 ----------------
__global__ __launch_bounds__(256) void rmsnorm_kernel(const float* __restrict__ x,
                                                      const float* __restrict__ g,
                                                      float* __restrict__ xn) {
    int row = blockIdx.x;
    int tid = threadIdx.x;
    const float4* xr = (const float4*)(x + (size_t)row * D_MODEL);
    float4 v = xr[tid];
    float ss = v.x*v.x + v.y*v.y + v.z*v.z + v.w*v.w;
    #pragma unroll
    for (int off = 32; off; off >>= 1) ss += __shfl_down(ss, off);
    __shared__ float red[4];
    if ((tid & 63) == 0) red[tid >> 6] = ss;
    __syncthreads();
    float tot = red[0] + red[1] + red[2] + red[3];
    float scale = rsqrtf(tot * (1.f / D_MODEL) + 1e-6f);
    float4 gv = ((const float4*)g)[tid];
    float4 o;
    o.x = v.x * scale * gv.x;
    o.y = v.y * scale * gv.y;
    o.z = v.z * scale * gv.z;
    o.w = v.w * scale * gv.w;
    ((float4*)(xn + (size_t)row * D_MODEL))[tid] = o;
}

// ---------- bf16-MFMA NT GEMM: C[m][n] = sum_k A[m][k]*B[n][k] (+resid) ----------
// BM=128, BN in {128,64}, BK=32. 256 threads = 4 waves (2x2). Verified r6:
// passed, absmax 0.0156.
template <int BN, int RESID>
__global__ __launch_bounds__(256) void gemm_bf16_nt(const float* __restrict__ A,
                                                    const float* __restrict__ B,
                                                    const float* __restrict__ resid,
                                                    float* __restrict__ C,
                                                    int M, int N, int K) {
    constexpr int BM = 128;
    constexpr int WN = BN / 2;
    constexpr int NJ = WN / 16;
    __shared__ short Asm[BM][40];
    __shared__ short Bsm[BN][40];
    int tid = threadIdx.x;
    int lane = tid & 63, w = tid >> 6;
    int wr = w >> 1, wc = w & 1;
    int bm = blockIdx.y * BM, bn = blockIdx.x * BN;
    int lrow = lane & 15, kg = (lane >> 4) * 8;
    f32x4 acc[4][NJ];
    #pragma unroll
    for (int i = 0; i < 4; i++)
        #pragma unroll
        for (int j = 0; j < NJ; j++)
            acc[i][j] = (f32x4){0.f, 0.f, 0.f, 0.f};

    for (int k0 = 0; k0 < K; k0 += 32) {
        #pragma unroll
        for (int c = tid; c < BM * 4; c += 256) {
            int row = c >> 2, ch = c & 3;
            const float* p = A + (size_t)(bm + row) * K + k0 + ch * 8;
            float4 v0 = *(const float4*)p;
            float4 v1 = *(const float4*)(p + 4);
            bf16x8 pk;
            pk[0] = f2bf(v0.x); pk[1] = f2bf(v0.y); pk[2] = f2bf(v0.z); pk[3] = f2bf(v0.w);
            pk[4] = f2bf(v1.x); pk[5] = f2bf(v1.y); pk[6] = f2bf(v1.z); pk[7] = f2bf(v1.w);
            *(bf16x8*)&Asm[row][ch * 8] = pk;
        }
        #pragma unroll
        for (int c = tid; c < BN * 4; c += 256) {
            int row = c >> 2, ch = c & 3;
            const float* p = B + (size_t)(bn + row) * K + k0 + ch * 8;
            float4 v0 = *(const float4*)p;
            float4 v1 = *(const float4*)(p + 4);
            bf16x8 pk;
            pk[0] = f2bf(v0.x); pk[1] = f2bf(v0.y); pk[2] = f2bf(v0.z); pk[3] = f2bf(v0.w);
            pk[4] = f2bf(v1.x); pk[5] = f2bf(v1.y); pk[6] = f2bf(v1.z); pk[7] = f2bf(v1.w);
            *(bf16x8*)&Bsm[row][ch * 8] = pk;
        }
        __syncthreads();
        bf16x8 aF[4], bF[NJ];
        #pragma unroll
        for (int i = 0; i < 4; i++)
            aF[i] = *(bf16x8*)&Asm[wr * 64 + i * 16 + lrow][kg];
        #pragma unroll
        for (int j = 0; j < NJ; j++)
            bF[j] = *(bf16x8*)&Bsm[wc * WN + j * 16 + lrow][kg];
        #pragma unroll
        for (int i = 0; i < 4; i++)
            #pragma unroll
            for (int j = 0; j < NJ; j++)
                acc[i][j] = __builtin_amdgcn_mfma_f32_16x16x32_bf16(aF[i], bF[j], acc[i][j], 0, 0, 0);
        __syncthreads();
    }
    #pragma unroll
    for (int i = 0; i < 4; i++)
        #pragma unroll
        for (int j = 0; j < NJ; j++)
            #pragma unroll
            for (int r = 0; r < 4; r++) {
                int m = bm + wr * 64 + i * 16 + (lane >> 4) * 4 + r;
                int n = bn + wc * WN + j * 16 + lrow;
                size_t off = (size_t)m * N + n;
                float v = acc[i][j][r];
                if (RESID) v += resid[off];
                C[off] = v;
            }
}

// ---------------- depthwise causal conv (K=4) + SiLU ----------------
__global__ __launch_bounds__(256) void conv_silu_kernel(const float* __restrict__ xz,
                                                        const float* __restrict__ cw,
                                                        const float* __restrict__ cb,
                                                        float* __restrict__ xc) {
    int idx = blockIdx.x * 256 + threadIdx.x;           // over NTOK*D_INNER
    int d  = idx & (D_INNER - 1);
    int bt = idx >> 11;                                  // b*TLEN + t
    int t  = bt & (TLEN - 1);
    float s = cb[d];
    #pragma unroll
    for (int j = 0; j < 4; j++) {
        int tt = t - 3 + j;
        if (tt >= 0)
            s += cw[d * 4 + j] * xz[(size_t)(bt - 3 + j) * (2 * D_INNER) + d];
    }
    xc[idx] = silu_f(s);
}

// ------------- params = xc @ W_x^T  (N=33), one block per token -------------
__global__ __launch_bounds__(256) void params_kernel(const float* __restrict__ xc,
                                                     const float* __restrict__ Wx,
                                                     float* __restrict__ params) {
    int token = blockIdx.x;
    int tid = threadIdx.x;
    const float4* xr = (const float4*)(xc + (size_t)token * D_INNER);
    float4 v0 = xr[tid * 2], v1 = xr[tid * 2 + 1];
    float v[8] = {v0.x, v0.y, v0.z, v0.w, v1.x, v1.y, v1.z, v1.w};
    float acc[33];
    #pragma unroll
    for (int n = 0; n < 33; n++) {
        const float* wr = Wx + (size_t)n * D_INNER + tid * 8;
        float4 w0 = *(const float4*)wr;
        float4 w1 = *(const float4*)(wr + 4);
        acc[n] = v[0]*w0.x + v[1]*w0.y + v[2]*w0.z + v[3]*w0.w
               + v[4]*w1.x + v[5]*w1.y + v[6]*w1.z + v[7]*w1.w;
    }
    __shared__ float red[4][33];
    #pragma unroll
    for (int n = 0; n < 33; n++) {
        float s = acc[n];
        s += __shfl_down(s, 32); s += __shfl_down(s, 16); s += __shfl_down(s, 8);
        s += __shfl_down(s, 4);  s += __shfl_down(s, 2);  s += __shfl_down(s, 1);
        if ((tid & 63) == 0) red[tid >> 6][n] = s;
    }
    __syncthreads();
    if (tid < 33)
        params[(size_t)token * 33 + tid] = red[0][tid] + red[1][tid] + red[2][tid] + red[3][tid];
}

// ---------------- chunked selective scan ----------------
// One 256-thread block per (b,d): thread = (chunk c in 0..15, state s in 0..15).
// Phase 1: local scan of 64-step chunk from h=0, tracking (aProd, hLocal).
// Phase 2: LDS exclusive cross-chunk combine -> h_init per chunk.
// Phase 3: re-scan chunk from h_init, emit y (shfl_xor reduce over 16 s-lanes).
// Parallelism: 4096 blocks x 4 waves = 16384 waves (vs 1024 before).
__global__ __launch_bounds__(256) void scan_kernel(const float* __restrict__ params,
                                                   const float* __restrict__ xc,
                                                   const float* __restrict__ xz,
                                                   const float* __restrict__ Wdt,
                                                   const float* __restrict__ bdt,
                                                   const float* __restrict__ Alog,
                                                   const float* __restrict__ Dp,
                                                   float* __restrict__ yact) {
    constexpr int L = TLEN / 16;            // 64 steps per chunk
    int tid = threadIdx.x;
    int s = tid & 15;
    int c = tid >> 4;                        // chunk 0..15
    int bd = blockIdx.x;                     // b*D_INNER + d
    int b = bd >> 11;
    int d = bd & (D_INNER - 1);
    int t0 = c * L;

    float A    = -__expf(Alog[d * D_STATE + s]);
    float wdt  = Wdt[d];
    float bdtd = bdt[d];
    float Dd   = Dp[d];

    const float* prow = params + ((size_t)b * TLEN + t0) * 33;
    const float* xcp  = xc + ((size_t)b * TLEN + t0) * D_INNER + d;
    const float* zp   = xz + ((size_t)b * TLEN + t0) * 2 * D_INNER + D_INNER + d;
    float* yp         = yact + ((size_t)b * TLEN + t0) * D_INNER + d;

    // ---- phase 1: local chunk scan from h=0 ----
    float h = 0.f, aP = 1.f;
    float Bc = prow[s], ldt = prow[32], xcv = xcp[0];
    for (int i = 0; i < L; i++) {
        float Bc1 = 0.f, ldt1 = 0.f, xcv1 = 0.f;
        if (i + 1 < L) {
            const float* pn = prow + (size_t)(i + 1) * 33;
            Bc1  = pn[s];
            ldt1 = pn[32];
            xcv1 = xcp[(size_t)(i + 1) * D_INNER];
        }
        float pre = ldt * wdt + bdtd;
        float dt  = (pre > 20.f) ? pre : log1pf(__expf(pre));
        float ab  = __expf(dt * A);
        h = ab * h + dt * Bc * xcv;
        aP *= ab;
        Bc = Bc1; ldt = ldt1; xcv = xcv1;
    }

    // ---- phase 2: cross-chunk exclusive combine in LDS ----
    __shared__ float sA[16][17];
    __shared__ float sH[16][17];
    sA[c][s] = aP;
    sH[c][s] = h;
    __syncthreads();
    float h0 = 0.f;
    for (int cc = 0; cc < c; cc++)
        h0 = sA[cc][s] * h0 + sH[cc][s];

    // ---- phase 3: re-scan chunk from h_init, emit y ----
    h = h0;
    Bc = prow[s];
    float Cc = prow[16 + s];
    ldt = prow[32];
    xcv = xcp[0];
    float zv = zp[0];
    for (int i = 0; i < L; i++) {
        float Bc1 = 0.f, Cc1 = 0.f, ldt1 = 0.f, xcv1 = 0.f, zv1 = 0.f;
        if (i + 1 < L) {
            const float* pn = prow + (size_t)(i + 1) * 33;
            Bc1  = pn[s];
            Cc1  = pn[16 + s];
            ldt1 = pn[32];
            xcv1 = xcp[(size_t)(i + 1) * D_INNER];
            zv1  = zp[(size_t)(i + 1) * 2 * D_INNER];
        }
        float pre = ldt * wdt + bdtd;
        float dt  = (pre > 20.f) ? pre : log1pf(__expf(pre));
        float ab  = __expf(dt * A);
        h = ab * h + dt * Bc * xcv;
        float y = h * Cc;
        y += __shfl_xor(y, 1); y += __shfl_xor(y, 2);
        y += __shfl_xor(y, 4); y += __shfl_xor(y, 8);
        if (s == 0)
            yp[(size_t)i * D_INNER] = (y + xcv * Dd) * silu_f(zv);
        Bc = Bc1; Cc = Cc1; ldt = ldt1; xcv = xcv1; zv = zv1;
    }
}

extern "C" void kernel_launch(void* const* d_in, const int* in_sizes, int n_in,
                              void* d_out, int out_size, void* d_ws, size_t ws_size,
                              hipStream_t stream) {
    const float* x      = (const float*)d_in[0];
    const float* g      = (const float*)d_in[1];
    const float* W_in   = (const float*)d_in[2];
    const float* W_out  = (const float*)d_in[3];
    const float* conv_w = (const float*)d_in[4];
    const float* conv_b = (const float*)d_in[5];
    const float* W_x    = (const float*)d_in[6];
    const float* W_dt   = (const float*)d_in[7];
    const float* b_dt   = (const float*)d_in[8];
    const float* A_log  = (const float*)d_in[9];
    const float* Dp     = (const float*)d_in[10];
    float* out = (float*)d_out;

    float* ws   = (float*)d_ws;
    float* xn   = ws;                                   // 2,097,152 f
    float* xz   = xn + (size_t)NTOK * D_MODEL;          // 8,388,608 f
    float* xc   = xz + (size_t)NTOK * 2 * D_INNER;      // 4,194,304 f
    float* par  = xc + (size_t)NTOK * D_INNER;          // 67,584 f
    float* yact = par + (size_t)NTOK * 33;              // 4,194,304 f

    rmsnorm_kernel<<<NTOK, 256, 0, stream>>>(x, g, xn);
    // GEMM1: M=2048, N=4096, K=1024 — bf16 MFMA, 128x128 tiles, 512 blocks
    gemm_bf16_nt<128, 0><<<dim3((2 * D_INNER) / 128, NTOK / 128), 256, 0, stream>>>(
        xn, W_in, nullptr, xz, NTOK, 2 * D_INNER, D_MODEL);
    conv_silu_kernel<<<(NTOK * D_INNER) / 256, 256, 0, stream>>>(xz, conv_w, conv_b, xc);
    params_kernel<<<NTOK, 256, 0, stream>>>(xc, W_x, par);
    // chunked scan: one block per (b,d)
    scan_kernel<<<BATCH * D_INNER, 256, 0, stream>>>(
        par, xc, xz, W_dt, b_dt, A_log, Dp, yact);
    // GEMM2: M=2048, N=1024, K=2048 — bf16 MFMA, 128x64 tiles, 256 blocks
    gemm_bf16_nt<64, 1><<<dim3(D_MODEL / 64, NTOK / 128), 256, 0, stream>>>(
        yact, W_out, x, out, NTOK, D_MODEL, D_INNER);
}

// Round 10
// 401.949 us; speedup vs baseline: 2.2961x; 1.9720x over previous
//
#include <hip/hip_runtime.h>
#include <hip/hip_bf16.h>
#include <math.h>

#define D_MODEL 1024
#define D_STATE 16
#define D_CONV  4
#define D_INNER 2048
#define TLEN    1024
#define BATCH   2
#define NTOK    (BATCH*TLEN)   // 2048
#define NCH     32             // scan chunks
#define CHL     (TLEN/NCH)     // 32 steps per chunk

typedef __attribute__((ext_vector_type(8))) short bf16x8;
typedef __attribute__((ext_vector_type(4))) float f32x4;

__device__ __forceinline__ float silu_f(float v) { return v / (1.f + __expf(-v)); }

// softplus: log1p(exp(x)) via hw exp/log; x~-6.9 here, guard large x
__device__ __forceinline__ float softplus_f(float x) {
    return (x > 15.f) ? x : __logf(1.f + __expf(x));
}

// fp32 -> bf16 (RNE), finite inputs
__device__ __forceinline__ short f2bf(float x) {
    unsigned u = __builtin_bit_cast(unsigned, x);
    unsigned r = (u + 0x7FFFu + ((u >> 16) & 1u)) >> 16;
    return (short)r;
}

// ---------------- RMSNorm: one block per token, 256 thr, float4 ----------------
__global__ __launch_bounds__(256) void rmsnorm_kernel(const float* __restrict__ x,
                                                      const float* __restrict__ g,
                                                      float* __restrict__ xn) {
    int row = blockIdx.x;
    int tid = threadIdx.x;
    const float4* xr = (const float4*)(x + (size_t)row * D_MODEL);
    float4 v = xr[tid];
    float ss = v.x*v.x + v.y*v.y + v.z*v.z + v.w*v.w;
    #pragma unroll
    for (int off = 32; off; off >>= 1) ss += __shfl_down(ss, off);
    __shared__ float red[4];
    if ((tid & 63) == 0) red[tid >> 6] = ss;
    __syncthreads();
    float tot = red[0] + red[1] + red[2] + red[3];
    float scale = rsqrtf(tot * (1.f / D_MODEL) + 1e-6f);
    float4 gv = ((const float4*)g)[tid];
    float4 o;
    o.x = v.x * scale * gv.x;
    o.y = v.y * scale * gv.y;
    o.z = v.z * scale * gv.z;
    o.w = v.w * scale * gv.w;
    ((float4*)(xn + (size_t)row * D_MODEL))[tid] = o;
}

// ---------- bf16-MFMA NT GEMM (verified r6: absmax 0.0156) ----------
template <int BN, int RESID>
__global__ __launch_bounds__(256) void gemm_bf16_nt(const float* __restrict__ A,
                                                    const float* __restrict__ B,
                                                    const float* __restrict__ resid,
                                                    float* __restrict__ C,
                                                    int M, int N, int K) {
    constexpr int BM = 128;
    constexpr int WN = BN / 2;
    constexpr int NJ = WN / 16;
    __shared__ short Asm[BM][40];
    __shared__ short Bsm[BN][40];
    int tid = threadIdx.x;
    int lane = tid & 63, w = tid >> 6;
    int wr = w >> 1, wc = w & 1;
    int bm = blockIdx.y * BM, bn = blockIdx.x * BN;
    int lrow = lane & 15, kg = (lane >> 4) * 8;
    f32x4 acc[4][NJ];
    #pragma unroll
    for (int i = 0; i < 4; i++)
        #pragma unroll
        for (int j = 0; j < NJ; j++)
            acc[i][j] = (f32x4){0.f, 0.f, 0.f, 0.f};

    for (int k0 = 0; k0 < K; k0 += 32) {
        #pragma unroll
        for (int c = tid; c < BM * 4; c += 256) {
            int row = c >> 2, ch = c & 3;
            const float* p = A + (size_t)(bm + row) * K + k0 + ch * 8;
            float4 v0 = *(const float4*)p;
            float4 v1 = *(const float4*)(p + 4);
            bf16x8 pk;
            pk[0] = f2bf(v0.x); pk[1] = f2bf(v0.y); pk[2] = f2bf(v0.z); pk[3] = f2bf(v0.w);
            pk[4] = f2bf(v1.x); pk[5] = f2bf(v1.y); pk[6] = f2bf(v1.z); pk[7] = f2bf(v1.w);
            *(bf16x8*)&Asm[row][ch * 8] = pk;
        }
        #pragma unroll
        for (int c = tid; c < BN * 4; c += 256) {
            int row = c >> 2, ch = c & 3;
            const float* p = B + (size_t)(bn + row) * K + k0 + ch * 8;
            float4 v0 = *(const float4*)p;
            float4 v1 = *(const float4*)(p + 4);
            bf16x8 pk;
            pk[0] = f2bf(v0.x); pk[1] = f2bf(v0.y); pk[2] = f2bf(v0.z); pk[3] = f2bf(v0.w);
            pk[4] = f2bf(v1.x); pk[5] = f2bf(v1.y); pk[6] = f2bf(v1.z); pk[7] = f2bf(v1.w);
            *(bf16x8*)&Bsm[row][ch * 8] = pk;
        }
        __syncthreads();
        bf16x8 aF[4], bF[NJ];
        #pragma unroll
        for (int i = 0; i < 4; i++)
            aF[i] = *(bf16x8*)&Asm[wr * 64 + i * 16 + lrow][kg];
        #pragma unroll
        for (int j = 0; j < NJ; j++)
            bF[j] = *(bf16x8*)&Bsm[wc * WN + j * 16 + lrow][kg];
        #pragma unroll
        for (int i = 0; i < 4; i++)
            #pragma unroll
            for (int j = 0; j < NJ; j++)
                acc[i][j] = __builtin_amdgcn_mfma_f32_16x16x32_bf16(aF[i], bF[j], acc[i][j], 0, 0, 0);
        __syncthreads();
    }
    #pragma unroll
    for (int i = 0; i < 4; i++)
        #pragma unroll
        for (int j = 0; j < NJ; j++)
            #pragma unroll
            for (int r = 0; r < 4; r++) {
                int m = bm + wr * 64 + i * 16 + (lane >> 4) * 4 + r;
                int n = bn + wc * WN + j * 16 + lrow;
                size_t off = (size_t)m * N + n;
                float v = acc[i][j][r];
                if (RESID) v += resid[off];
                C[off] = v;
            }
}

// ---------------- depthwise causal conv (K=4) + SiLU ----------------
__global__ __launch_bounds__(256) void conv_silu_kernel(const float* __restrict__ xz,
                                                        const float* __restrict__ cw,
                                                        const float* __restrict__ cb,
                                                        float* __restrict__ xc) {
    int idx = blockIdx.x * 256 + threadIdx.x;           // over NTOK*D_INNER
    int d  = idx & (D_INNER - 1);
    int bt = idx >> 11;                                  // b*TLEN + t
    int t  = bt & (TLEN - 1);
    float s = cb[d];
    #pragma unroll
    for (int j = 0; j < 4; j++) {
        int tt = t - 3 + j;
        if (tt >= 0)
            s += cw[d * 4 + j] * xz[(size_t)(bt - 3 + j) * (2 * D_INNER) + d];
    }
    xc[idx] = silu_f(s);
}

// ------------- params = xc @ W_x^T  (N=33), one block per token -------------
__global__ __launch_bounds__(256) void params_kernel(const float* __restrict__ xc,
                                                     const float* __restrict__ Wx,
                                                     float* __restrict__ params) {
    int token = blockIdx.x;
    int tid = threadIdx.x;
    const float4* xr = (const float4*)(xc + (size_t)token * D_INNER);
    float4 v0 = xr[tid * 2], v1 = xr[tid * 2 + 1];
    float v[8] = {v0.x, v0.y, v0.z, v0.w, v1.x, v1.y, v1.z, v1.w};
    float acc[33];
    #pragma unroll
    for (int n = 0; n < 33; n++) {
        const float* wr = Wx + (size_t)n * D_INNER + tid * 8;
        float4 w0 = *(const float4*)wr;
        float4 w1 = *(const float4*)(wr + 4);
        acc[n] = v[0]*w0.x + v[1]*w0.y + v[2]*w0.z + v[3]*w0.w
               + v[4]*w1.x + v[5]*w1.y + v[6]*w1.z + v[7]*w1.w;
    }
    __shared__ float red[4][33];
    #pragma unroll
    for (int n = 0; n < 33; n++) {
        float s = acc[n];
        s += __shfl_down(s, 32); s += __shfl_down(s, 16); s += __shfl_down(s, 8);
        s += __shfl_down(s, 4);  s += __shfl_down(s, 2);  s += __shfl_down(s, 1);
        if ((tid & 63) == 0) red[tid >> 6][n] = s;
    }
    __syncthreads();
    if (tid < 33)
        params[(size_t)token * 33 + tid] = red[0][tid] + red[1][tid] + red[2][tid] + red[3][tid];
}

// ================= chunked scan, thread-per-d layout =================
// S1: block = (dtile 256, chunk, b); thread owns d with h[16] in regs.
//     params chunk staged in LDS (broadcast); xc coalesced.
//     Emits h_local[b][ch][d][s] and sumdt[b][ch][d]  (prod exp = exp(A*sumdt)).
__global__ __launch_bounds__(256) void scan_phase1(const float* __restrict__ params,
                                                   const float* __restrict__ xc,
                                                   const float* __restrict__ Wdt,
                                                   const float* __restrict__ bdt,
                                                   const float* __restrict__ Alog,
                                                   float* __restrict__ hloc,
                                                   float* __restrict__ sdbuf) {
    __shared__ float sP[CHL * 36];      // 36-stride keeps float4 16B-aligned
    int tid = threadIdx.x;
    int d  = blockIdx.x * 256 + tid;
    int ch = blockIdx.y;
    int b  = blockIdx.z;
    int t0 = ch * CHL;

    const float* pbase = params + ((size_t)b * TLEN + t0) * 33;
    for (int i = tid; i < CHL * 33; i += 256)
        sP[(i / 33) * 36 + (i % 33)] = pbase[i];
    __syncthreads();

    float A[16];
    #pragma unroll
    for (int s = 0; s < 16; s++) A[s] = -__expf(Alog[d * 16 + s]);
    float wdt = Wdt[d], bdtd = bdt[d];

    float h[16];
    #pragma unroll
    for (int s = 0; s < 16; s++) h[s] = 0.f;
    float sumdt = 0.f;

    const float* xcp = xc + ((size_t)b * TLEN + t0) * D_INNER + d;
    for (int i = 0; i < CHL; i++) {
        float ldt = sP[i * 36 + 32];
        float xcv = xcp[(size_t)i * D_INNER];
        float dt  = softplus_f(ldt * wdt + bdtd);
        sumdt += dt;
        float m = dt * xcv;
        float4 B0 = *(const float4*)&sP[i * 36 + 0];
        float4 B1 = *(const float4*)&sP[i * 36 + 4];
        float4 B2 = *(const float4*)&sP[i * 36 + 8];
        float4 B3 = *(const float4*)&sP[i * 36 + 12];
        float Bv[16] = {B0.x,B0.y,B0.z,B0.w, B1.x,B1.y,B1.z,B1.w,
                        B2.x,B2.y,B2.z,B2.w, B3.x,B3.y,B3.z,B3.w};
        #pragma unroll
        for (int s = 0; s < 16; s++) {
            float ab = __expf(dt * A[s]);
            h[s] = ab * h[s] + m * Bv[s];
        }
    }
    size_t base = ((size_t)(b * NCH + ch) * D_INNER + d);
    sdbuf[base] = sumdt;
    float* hp = hloc + base * 16;
    #pragma unroll
    for (int q = 0; q < 4; q++)
        *(float4*)&hp[q * 4] = (float4){h[q*4], h[q*4+1], h[q*4+2], h[q*4+3]};
}

// S2: serial prefix over chunks per (b,d,s) -> h_init (exclusive).
__global__ __launch_bounds__(256) void scan_combine(const float* __restrict__ hloc,
                                                    const float* __restrict__ sdbuf,
                                                    const float* __restrict__ Alog,
                                                    float* __restrict__ hini) {
    int idx = blockIdx.x * 256 + threadIdx.x;   // over B*D_INNER*16
    int s = idx & 15;
    int d = (idx >> 4) & (D_INNER - 1);
    int b = idx >> 15;
    float As = -__expf(Alog[d * 16 + s]);
    float h0 = 0.f;
    for (int ch = 0; ch < NCH; ch++) {
        size_t base = ((size_t)(b * NCH + ch) * D_INNER + d);
        hini[base * 16 + s] = h0;
        float aP = __expf(As * sdbuf[base]);
        h0 = aP * h0 + hloc[base * 16 + s];
    }
}

// S3: re-scan chunk from h_init; y accumulated in-thread; coalesced I/O.
__global__ __launch_bounds__(256) void scan_phase3(const float* __restrict__ params,
                                                   const float* __restrict__ xc,
                                                   const float* __restrict__ xz,
                                                   const float* __restrict__ Wdt,
                                                   const float* __restrict__ bdt,
                                                   const float* __restrict__ Alog,
                                                   const float* __restrict__ Dp,
                                                   const float* __restrict__ hini,
                                                   float* __restrict__ yact) {
    __shared__ float sP[CHL * 36];
    int tid = threadIdx.x;
    int d  = blockIdx.x * 256 + tid;
    int ch = blockIdx.y;
    int b  = blockIdx.z;
    int t0 = ch * CHL;

    const float* pbase = params + ((size_t)b * TLEN + t0) * 33;
    for (int i = tid; i < CHL * 33; i += 256)
        sP[(i / 33) * 36 + (i % 33)] = pbase[i];
    __syncthreads();

    float A[16];
    #pragma unroll
    for (int s = 0; s < 16; s++) A[s] = -__expf(Alog[d * 16 + s]);
    float wdt = Wdt[d], bdtd = bdt[d], Dd = Dp[d];

    float h[16];
    const float* hp = hini + ((size_t)(b * NCH + ch) * D_INNER + d) * 16;
    #pragma unroll
    for (int q = 0; q < 4; q++) {
        float4 hv = *(const float4*)&hp[q * 4];
        h[q*4] = hv.x; h[q*4+1] = hv.y; h[q*4+2] = hv.z; h[q*4+3] = hv.w;
    }

    const float* xcp = xc + ((size_t)b * TLEN + t0) * D_INNER + d;
    const float* zp  = xz + ((size_t)b * TLEN + t0) * 2 * D_INNER + D_INNER + d;
    float* yp        = yact + ((size_t)b * TLEN + t0) * D_INNER + d;
    for (int i = 0; i < CHL; i++) {
        float ldt = sP[i * 36 + 32];
        float xcv = xcp[(size_t)i * D_INNER];
        float zv  = zp[(size_t)i * 2 * D_INNER];
        float dt  = softplus_f(ldt * wdt + bdtd);
        float m = dt * xcv;
        float4 B0 = *(const float4*)&sP[i * 36 + 0];
        float4 B1 = *(const float4*)&sP[i * 36 + 4];
        float4 B2 = *(const float4*)&sP[i * 36 + 8];
        float4 B3 = *(const float4*)&sP[i * 36 + 12];
        float4 C0 = *(const float4*)&sP[i * 36 + 16];
        float4 C1 = *(const float4*)&sP[i * 36 + 20];
        float4 C2 = *(const float4*)&sP[i * 36 + 24];
        float4 C3 = *(const float4*)&sP[i * 36 + 28];
        float Bv[16] = {B0.x,B0.y,B0.z,B0.w, B1.x,B1.y,B1.z,B1.w,
                        B2.x,B2.y,B2.z,B2.w, B3.x,B3.y,B3.z,B3.w};
        float Cv[16] = {C0.x,C0.y,C0.z,C0.w, C1.x,C1.y,C1.z,C1.w,
                        C2.x,C2.y,C2.z,C2.w, C3.x,C3.y,C3.z,C3.w};
        float y = 0.f;
        #pragma unroll
        for (int s = 0; s < 16; s++) {
            float ab = __expf(dt * A[s]);
            h[s] = ab * h[s] + m * Bv[s];
            y += h[s] * Cv[s];
        }
        yp[(size_t)i * D_INNER] = (y + xcv * Dd) * silu_f(zv);
    }
}

extern "C" void kernel_launch(void* const* d_in, const int* in_sizes, int n_in,
                              void* d_out, int out_size, void* d_ws, size_t ws_size,
                              hipStream_t stream) {
    const float* x      = (const float*)d_in[0];
    const float* g      = (const float*)d_in[1];
    const float* W_in   = (const float*)d_in[2];
    const float* W_out  = (const float*)d_in[3];
    const float* conv_w = (const float*)d_in[4];
    const float* conv_b = (const float*)d_in[5];
    const float* W_x    = (const float*)d_in[6];
    const float* W_dt   = (const float*)d_in[7];
    const float* b_dt   = (const float*)d_in[8];
    const float* A_log  = (const float*)d_in[9];
    const float* Dp     = (const float*)d_in[10];
    float* out = (float*)d_out;

    float* ws   = (float*)d_ws;
    float* xn   = ws;                                   // 2,097,152 f (dead after GEMM1)
    float* xz   = xn + (size_t)NTOK * D_MODEL;          // 8,388,608 f
    float* xc   = xz + (size_t)NTOK * 2 * D_INNER;      // 4,194,304 f
    float* par  = xc + (size_t)NTOK * D_INNER;          // 67,584 f
    float* yact = par + (size_t)NTOK * 33;              // 4,194,304 f
    float* hloc = xn;                                   // overlay: 2,097,152 f, used after xn dies
    float* hini = yact + (size_t)NTOK * D_INNER;        // 2,097,152 f
    float* sd   = hini + (size_t)BATCH * NCH * D_INNER * 16; // 131,072 f

    rmsnorm_kernel<<<NTOK, 256, 0, stream>>>(x, g, xn);
    gemm_bf16_nt<128, 0><<<dim3((2 * D_INNER) / 128, NTOK / 128), 256, 0, stream>>>(
        xn, W_in, nullptr, xz, NTOK, 2 * D_INNER, D_MODEL);
    conv_silu_kernel<<<(NTOK * D_INNER) / 256, 256, 0, stream>>>(xz, conv_w, conv_b, xc);
    params_kernel<<<NTOK, 256, 0, stream>>>(xc, W_x, par);

    dim3 sgrid(D_INNER / 256, NCH, BATCH);
    scan_phase1<<<sgrid, 256, 0, stream>>>(par, xc, W_dt, b_dt, A_log, hloc, sd);
    scan_combine<<<(BATCH * D_INNER * 16) / 256, 256, 0, stream>>>(hloc, sd, A_log, hini);
    scan_phase3<<<sgrid, 256, 0, stream>>>(par, xc, xz, W_dt, b_dt, A_log, Dp, hini, yact);

    gemm_bf16_nt<64, 1><<<dim3(D_MODEL / 64, NTOK / 128), 256, 0, stream>>>(
        yact, W_out, x, out, NTOK, D_MODEL, D_INNER);
}

// Round 11
// 331.386 us; speedup vs baseline: 2.7850x; 1.2129x over previous
//
#include <hip/hip_runtime.h>
#include <hip/hip_bf16.h>
#include <math.h>

#define D_MODEL 1024
#define D_STATE 16
#define D_CONV  4
#define D_INNER 2048
#define TLEN    1024
#define BATCH   2
#define NTOK    (BATCH*TLEN)   // 2048
#define NCH     32             // scan chunks
#define CHL     (TLEN/NCH)     // 32 steps per chunk

typedef __attribute__((ext_vector_type(8))) short bf16x8;
typedef __attribute__((ext_vector_type(4))) float f32x4;

__device__ __forceinline__ float silu_f(float v) { return v / (1.f + __expf(-v)); }

__device__ __forceinline__ float softplus_f(float x) {
    return (x > 15.f) ? x : __logf(1.f + __expf(x));
}

// fp32 -> bf16 (RNE), finite inputs
__device__ __forceinline__ short f2bf(float x) {
    unsigned u = __builtin_bit_cast(unsigned, x);
    unsigned r = (u + 0x7FFFu + ((u >> 16) & 1u)) >> 16;
    return (short)r;
}

// ---------------- fp32 -> bf16 bulk convert (weights, once per call) ----------------
__global__ __launch_bounds__(256) void cvt_bf16_kernel(const float* __restrict__ in,
                                                       short* __restrict__ out) {
    int idx = (blockIdx.x * 256 + threadIdx.x) * 8;
    float4 v0 = *(const float4*)(in + idx);
    float4 v1 = *(const float4*)(in + idx + 4);
    bf16x8 pk;
    pk[0] = f2bf(v0.x); pk[1] = f2bf(v0.y); pk[2] = f2bf(v0.z); pk[3] = f2bf(v0.w);
    pk[4] = f2bf(v1.x); pk[5] = f2bf(v1.y); pk[6] = f2bf(v1.z); pk[7] = f2bf(v1.w);
    *(bf16x8*)(out + idx) = pk;
}

// ---------------- RMSNorm: one block per token, emits bf16 ----------------
__global__ __launch_bounds__(256) void rmsnorm_kernel(const float* __restrict__ x,
                                                      const float* __restrict__ g,
                                                      short* __restrict__ xn_bf) {
    int row = blockIdx.x;
    int tid = threadIdx.x;
    const float4* xr = (const float4*)(x + (size_t)row * D_MODEL);
    float4 v = xr[tid];
    float ss = v.x*v.x + v.y*v.y + v.z*v.z + v.w*v.w;
    #pragma unroll
    for (int off = 32; off; off >>= 1) ss += __shfl_down(ss, off);
    __shared__ float red[4];
    if ((tid & 63) == 0) red[tid >> 6] = ss;
    __syncthreads();
    float tot = red[0] + red[1] + red[2] + red[3];
    float scale = rsqrtf(tot * (1.f / D_MODEL) + 1e-6f);
    float4 gv = ((const float4*)g)[tid];
    short4 o;
    o.x = f2bf(v.x * scale * gv.x);
    o.y = f2bf(v.y * scale * gv.y);
    o.z = f2bf(v.z * scale * gv.z);
    o.w = f2bf(v.w * scale * gv.w);
    *(short4*)(xn_bf + (size_t)row * D_MODEL + tid * 4) = o;
}

// ---------- bf16-in MFMA NT GEMM: C[m][n] = sum_k A[m][k]*B[n][k] (+resid) ----------
// A,B already bf16. 256 threads = 4 waves in 2x2; wave tile = (BM/2)x(BN/2).
// BK=32; LDS rows padded to 40 shorts (2-way bank alias = free).
// Fragment maps m89-verified (r6: absmax 0.0156).
template <int BM, int BN, int RESID>
__global__ __launch_bounds__(256) void gemm_bf16_nt(const short* __restrict__ A,
                                                    const short* __restrict__ B,
                                                    const float* __restrict__ resid,
                                                    float* __restrict__ C,
                                                    int M, int N, int K) {
    constexpr int WRm = BM / 2;         // wave rows
    constexpr int WCn = BN / 2;         // wave cols
    constexpr int MI = WRm / 16;
    constexpr int NJ = WCn / 16;
    __shared__ short Asm[BM][40];
    __shared__ short Bsm[BN][40];
    int tid = threadIdx.x;
    int lane = tid & 63, w = tid >> 6;
    int wr = w >> 1, wc = w & 1;
    int bm = blockIdx.y * BM, bn = blockIdx.x * BN;
    int lrow = lane & 15, kg = (lane >> 4) * 8;
    f32x4 acc[MI][NJ];
    #pragma unroll
    for (int i = 0; i < MI; i++)
        #pragma unroll
        for (int j = 0; j < NJ; j++)
            acc[i][j] = (f32x4){0.f, 0.f, 0.f, 0.f};

    for (int k0 = 0; k0 < K; k0 += 32) {
        #pragma unroll
        for (int c = tid; c < BM * 4; c += 256) {
            int row = c >> 2, q = c & 3;
            *(bf16x8*)&Asm[row][q * 8] =
                *(const bf16x8*)(A + (size_t)(bm + row) * K + k0 + q * 8);
        }
        #pragma unroll
        for (int c = tid; c < BN * 4; c += 256) {
            int row = c >> 2, q = c & 3;
            *(bf16x8*)&Bsm[row][q * 8] =
                *(const bf16x8*)(B + (size_t)(bn + row) * K + k0 + q * 8);
        }
        __syncthreads();
        bf16x8 aF[MI], bF[NJ];
        #pragma unroll
        for (int i = 0; i < MI; i++)
            aF[i] = *(bf16x8*)&Asm[wr * WRm + i * 16 + lrow][kg];
        #pragma unroll
        for (int j = 0; j < NJ; j++)
            bF[j] = *(bf16x8*)&Bsm[wc * WCn + j * 16 + lrow][kg];
        #pragma unroll
        for (int i = 0; i < MI; i++)
            #pragma unroll
            for (int j = 0; j < NJ; j++)
                acc[i][j] = __builtin_amdgcn_mfma_f32_16x16x32_bf16(aF[i], bF[j], acc[i][j], 0, 0, 0);
        __syncthreads();
    }
    #pragma unroll
    for (int i = 0; i < MI; i++)
        #pragma unroll
        for (int j = 0; j < NJ; j++)
            #pragma unroll
            for (int r = 0; r < 4; r++) {
                int m = bm + wr * WRm + i * 16 + (lane >> 4) * 4 + r;
                int n = bn + wc * WCn + j * 16 + lrow;
                size_t off = (size_t)m * N + n;
                float v = acc[i][j][r];
                if (RESID) v += resid[off];
                C[off] = v;
            }
}

// ---------------- depthwise causal conv (K=4) + SiLU ----------------
__global__ __launch_bounds__(256) void conv_silu_kernel(const float* __restrict__ xz,
                                                        const float* __restrict__ cw,
                                                        const float* __restrict__ cb,
                                                        float* __restrict__ xc) {
    int idx = blockIdx.x * 256 + threadIdx.x;           // over NTOK*D_INNER
    int d  = idx & (D_INNER - 1);
    int bt = idx >> 11;                                  // b*TLEN + t
    int t  = bt & (TLEN - 1);
    float s = cb[d];
    #pragma unroll
    for (int j = 0; j < 4; j++) {
        int tt = t - 3 + j;
        if (tt >= 0)
            s += cw[d * 4 + j] * xz[(size_t)(bt - 3 + j) * (2 * D_INNER) + d];
    }
    xc[idx] = silu_f(s);
}

// ------------- params = xc @ W_x^T  (N=33), one block per token -------------
__global__ __launch_bounds__(256) void params_kernel(const float* __restrict__ xc,
                                                     const float* __restrict__ Wx,
                                                     float* __restrict__ params) {
    int token = blockIdx.x;
    int tid = threadIdx.x;
    const float4* xr = (const float4*)(xc + (size_t)token * D_INNER);
    float4 v0 = xr[tid * 2], v1 = xr[tid * 2 + 1];
    float v[8] = {v0.x, v0.y, v0.z, v0.w, v1.x, v1.y, v1.z, v1.w};
    float acc[33];
    #pragma unroll
    for (int n = 0; n < 33; n++) {
        const float* wr = Wx + (size_t)n * D_INNER + tid * 8;
        float4 w0 = *(const float4*)wr;
        float4 w1 = *(const float4*)(wr + 4);
        acc[n] = v[0]*w0.x + v[1]*w0.y + v[2]*w0.z + v[3]*w0.w
               + v[4]*w1.x + v[5]*w1.y + v[6]*w1.z + v[7]*w1.w;
    }
    __shared__ float red[4][33];
    #pragma unroll
    for (int n = 0; n < 33; n++) {
        float s = acc[n];
        s += __shfl_down(s, 32); s += __shfl_down(s, 16); s += __shfl_down(s, 8);
        s += __shfl_down(s, 4);  s += __shfl_down(s, 2);  s += __shfl_down(s, 1);
        if ((tid & 63) == 0) red[tid >> 6][n] = s;
    }
    __syncthreads();
    if (tid < 33)
        params[(size_t)token * 33 + tid] = red[0][tid] + red[1][tid] + red[2][tid] + red[3][tid];
}

// ================= chunked scan, thread-per-d layout (verified r10) =================
__global__ __launch_bounds__(256) void scan_phase1(const float* __restrict__ params,
                                                   const float* __restrict__ xc,
                                                   const float* __restrict__ Wdt,
                                                   const float* __restrict__ bdt,
                                                   const float* __restrict__ Alog,
                                                   float* __restrict__ hloc,
                                                   float* __restrict__ sdbuf) {
    __shared__ float sP[CHL * 36];
    int tid = threadIdx.x;
    int d  = blockIdx.x * 256 + tid;
    int ch = blockIdx.y;
    int b  = blockIdx.z;
    int t0 = ch * CHL;

    const float* pbase = params + ((size_t)b * TLEN + t0) * 33;
    for (int i = tid; i < CHL * 33; i += 256)
        sP[(i / 33) * 36 + (i % 33)] = pbase[i];
    __syncthreads();

    float A[16];
    #pragma unroll
    for (int s = 0; s < 16; s++) A[s] = -__expf(Alog[d * 16 + s]);
    float wdt = Wdt[d], bdtd = bdt[d];

    float h[16];
    #pragma unroll
    for (int s = 0; s < 16; s++) h[s] = 0.f;
    float sumdt = 0.f;

    const float* xcp = xc + ((size_t)b * TLEN + t0) * D_INNER + d;
    for (int i = 0; i < CHL; i++) {
        float ldt = sP[i * 36 + 32];
        float xcv = xcp[(size_t)i * D_INNER];
        float dt  = softplus_f(ldt * wdt + bdtd);
        sumdt += dt;
        float m = dt * xcv;
        float4 B0 = *(const float4*)&sP[i * 36 + 0];
        float4 B1 = *(const float4*)&sP[i * 36 + 4];
        float4 B2 = *(const float4*)&sP[i * 36 + 8];
        float4 B3 = *(const float4*)&sP[i * 36 + 12];
        float Bv[16] = {B0.x,B0.y,B0.z,B0.w, B1.x,B1.y,B1.z,B1.w,
                        B2.x,B2.y,B2.z,B2.w, B3.x,B3.y,B3.z,B3.w};
        #pragma unroll
        for (int s = 0; s < 16; s++) {
            float ab = __expf(dt * A[s]);
            h[s] = ab * h[s] + m * Bv[s];
        }
    }
    size_t base = ((size_t)(b * NCH + ch) * D_INNER + d);
    sdbuf[base] = sumdt;
    float* hp = hloc + base * 16;
    #pragma unroll
    for (int q = 0; q < 4; q++)
        *(float4*)&hp[q * 4] = (float4){h[q*4], h[q*4+1], h[q*4+2], h[q*4+3]};
}

__global__ __launch_bounds__(256) void scan_combine(const float* __restrict__ hloc,
                                                    const float* __restrict__ sdbuf,
                                                    const float* __restrict__ Alog,
                                                    float* __restrict__ hini) {
    int idx = blockIdx.x * 256 + threadIdx.x;   // over B*D_INNER*16
    int s = idx & 15;
    int d = (idx >> 4) & (D_INNER - 1);
    int b = idx >> 15;
    float As = -__expf(Alog[d * 16 + s]);
    float h0 = 0.f;
    for (int ch = 0; ch < NCH; ch++) {
        size_t base = ((size_t)(b * NCH + ch) * D_INNER + d);
        hini[base * 16 + s] = h0;
        float aP = __expf(As * sdbuf[base]);
        h0 = aP * h0 + hloc[base * 16 + s];
    }
}

// S3: re-scan chunk from h_init; emits y as bf16 (feeds GEMM2 A-operand).
__global__ __launch_bounds__(256) void scan_phase3(const float* __restrict__ params,
                                                   const float* __restrict__ xc,
                                                   const float* __restrict__ xz,
                                                   const float* __restrict__ Wdt,
                                                   const float* __restrict__ bdt,
                                                   const float* __restrict__ Alog,
                                                   const float* __restrict__ Dp,
                                                   const float* __restrict__ hini,
                                                   short* __restrict__ y_bf) {
    __shared__ float sP[CHL * 36];
    int tid = threadIdx.x;
    int d  = blockIdx.x * 256 + tid;
    int ch = blockIdx.y;
    int b  = blockIdx.z;
    int t0 = ch * CHL;

    const float* pbase = params + ((size_t)b * TLEN + t0) * 33;
    for (int i = tid; i < CHL * 33; i += 256)
        sP[(i / 33) * 36 + (i % 33)] = pbase[i];
    __syncthreads();

    float A[16];
    #pragma unroll
    for (int s = 0; s < 16; s++) A[s] = -__expf(Alog[d * 16 + s]);
    float wdt = Wdt[d], bdtd = bdt[d], Dd = Dp[d];

    float h[16];
    const float* hp = hini + ((size_t)(b * NCH + ch) * D_INNER + d) * 16;
    #pragma unroll
    for (int q = 0; q < 4; q++) {
        float4 hv = *(const float4*)&hp[q * 4];
        h[q*4] = hv.x; h[q*4+1] = hv.y; h[q*4+2] = hv.z; h[q*4+3] = hv.w;
    }

    const float* xcp = xc + ((size_t)b * TLEN + t0) * D_INNER + d;
    const float* zp  = xz + ((size_t)b * TLEN + t0) * 2 * D_INNER + D_INNER + d;
    short* yp        = y_bf + ((size_t)b * TLEN + t0) * D_INNER + d;
    for (int i = 0; i < CHL; i++) {
        float ldt = sP[i * 36 + 32];
        float xcv = xcp[(size_t)i * D_INNER];
        float zv  = zp[(size_t)i * 2 * D_INNER];
        float dt  = softplus_f(ldt * wdt + bdtd);
        float m = dt * xcv;
        float4 B0 = *(const float4*)&sP[i * 36 + 0];
        float4 B1 = *(const float4*)&sP[i * 36 + 4];
        float4 B2 = *(const float4*)&sP[i * 36 + 8];
        float4 B3 = *(const float4*)&sP[i * 36 + 12];
        float4 C0 = *(const float4*)&sP[i * 36 + 16];
        float4 C1 = *(const float4*)&sP[i * 36 + 20];
        float4 C2 = *(const float4*)&sP[i * 36 + 24];
        float4 C3 = *(const float4*)&sP[i * 36 + 28];
        float Bv[16] = {B0.x,B0.y,B0.z,B0.w, B1.x,B1.y,B1.z,B1.w,
                        B2.x,B2.y,B2.z,B2.w, B3.x,B3.y,B3.z,B3.w};
        float Cv[16] = {C0.x,C0.y,C0.z,C0.w, C1.x,C1.y,C1.z,C1.w,
                        C2.x,C2.y,C2.z,C2.w, C3.x,C3.y,C3.z,C3.w};
        float y = 0.f;
        #pragma unroll
        for (int s = 0; s < 16; s++) {
            float ab = __expf(dt * A[s]);
            h[s] = ab * h[s] + m * Bv[s];
            y += h[s] * Cv[s];
        }
        yp[(size_t)i * D_INNER] = f2bf((y + xcv * Dd) * silu_f(zv));
    }
}

extern "C" void kernel_launch(void* const* d_in, const int* in_sizes, int n_in,
                              void* d_out, int out_size, void* d_ws, size_t ws_size,
                              hipStream_t stream) {
    const float* x      = (const float*)d_in[0];
    const float* g      = (const float*)d_in[1];
    const float* W_in   = (const float*)d_in[2];
    const float* W_out  = (const float*)d_in[3];
    const float* conv_w = (const float*)d_in[4];
    const float* conv_b = (const float*)d_in[5];
    const float* W_x    = (const float*)d_in[6];
    const float* W_dt   = (const float*)d_in[7];
    const float* b_dt   = (const float*)d_in[8];
    const float* A_log  = (const float*)d_in[9];
    const float* Dp     = (const float*)d_in[10];
    float* out = (float*)d_out;

    // workspace layout (84.7 MB total, same footprint as r10):
    float* ws    = (float*)d_ws;
    float* hloc  = ws;                                        // 2,097,152 f
    float* xz    = ws + 2097152;                              // 8,388,608 f
    float* xc    = ws + 10485760;                             // 4,194,304 f
    float* par   = ws + 14680064;                             // 67,584 f
    short* y_bf  = (short*)(ws + 14747648);                   // 4,194,304 s
    short* xn_bf = (short*)(ws + 16844800);                   // 2,097,152 s
    short* wbf_o = (short*)(ws + 17893376);                   // 2,097,152 s (W_out bf16)
    float* hini  = ws + 18941952;                             // 2,097,152 f
    short* wbf_i = (short*)hini;                              // W_in bf16 overlays hini
                                                              //  (dead before S2 writes hini)
    float* sd    = ws + 21039104;                             // 131,072 f

    // one-shot weight conversion
    cvt_bf16_kernel<<<(2 * D_INNER * D_MODEL) / (256 * 8), 256, 0, stream>>>(W_in, wbf_i);
    cvt_bf16_kernel<<<(D_MODEL * D_INNER) / (256 * 8), 256, 0, stream>>>(W_out, wbf_o);

    rmsnorm_kernel<<<NTOK, 256, 0, stream>>>(x, g, xn_bf);
    // GEMM1: M=2048, N=4096, K=1024 — 128x128, 512 blocks
    gemm_bf16_nt<128, 128, 0><<<dim3((2 * D_INNER) / 128, NTOK / 128), 256, 0, stream>>>(
        xn_bf, wbf_i, nullptr, xz, NTOK, 2 * D_INNER, D_MODEL);
    conv_silu_kernel<<<(NTOK * D_INNER) / 256, 256, 0, stream>>>(xz, conv_w, conv_b, xc);
    params_kernel<<<NTOK, 256, 0, stream>>>(xc, W_x, par);

    dim3 sgrid(D_INNER / 256, NCH, BATCH);
    scan_phase1<<<sgrid, 256, 0, stream>>>(par, xc, W_dt, b_dt, A_log, hloc, sd);
    scan_combine<<<(BATCH * D_INNER * 16) / 256, 256, 0, stream>>>(hloc, sd, A_log, hini);
    scan_phase3<<<sgrid, 256, 0, stream>>>(par, xc, xz, W_dt, b_dt, A_log, Dp, hini, y_bf);

    // GEMM2: M=2048, N=1024, K=2048 — 64x64, 512 blocks (2 blocks/CU)
    gemm_bf16_nt<64, 64, 1><<<dim3(D_MODEL / 64, NTOK / 64), 256, 0, stream>>>(
        y_bf, wbf_o, x, out, NTOK, D_MODEL, D_INNER);
}

// Round 12
// 329.492 us; speedup vs baseline: 2.8010x; 1.0057x over previous
//
#include <hip/hip_runtime.h>
#include <hip/hip_bf16.h>
#include <math.h>

#define D_MODEL 1024
#define D_STATE 16
#define D_CONV  4
#define D_INNER 2048
#define TLEN    1024
#define BATCH   2
#define NTOK    (BATCH*TLEN)   // 2048
#define NCH     32             // scan chunks
#define CHL     (TLEN/NCH)     // 32 steps per chunk

typedef __attribute__((ext_vector_type(8))) short bf16x8;
typedef __attribute__((ext_vector_type(4))) float f32x4;

__device__ __forceinline__ float silu_f(float v) { return v / (1.f + __expf(-v)); }

__device__ __forceinline__ float softplus_f(float x) {
    return (x > 15.f) ? x : __logf(1.f + __expf(x));
}

// fp32 -> bf16 (RNE), finite inputs
__device__ __forceinline__ short f2bf(float x) {
    unsigned u = __builtin_bit_cast(unsigned, x);
    unsigned r = (u + 0x7FFFu + ((u >> 16) & 1u)) >> 16;
    return (short)r;
}

// ---------------- fp32 -> bf16 bulk convert (weights, once per call) ----------------
__global__ __launch_bounds__(256) void cvt_bf16_kernel(const float* __restrict__ in,
                                                       short* __restrict__ out) {
    int idx = (blockIdx.x * 256 + threadIdx.x) * 8;
    float4 v0 = *(const float4*)(in + idx);
    float4 v1 = *(const float4*)(in + idx + 4);
    bf16x8 pk;
    pk[0] = f2bf(v0.x); pk[1] = f2bf(v0.y); pk[2] = f2bf(v0.z); pk[3] = f2bf(v0.w);
    pk[4] = f2bf(v1.x); pk[5] = f2bf(v1.y); pk[6] = f2bf(v1.z); pk[7] = f2bf(v1.w);
    *(bf16x8*)(out + idx) = pk;
}

// ---------------- RMSNorm: one block per token, emits bf16 ----------------
__global__ __launch_bounds__(256) void rmsnorm_kernel(const float* __restrict__ x,
                                                      const float* __restrict__ g,
                                                      short* __restrict__ xn_bf) {
    int row = blockIdx.x;
    int tid = threadIdx.x;
    const float4* xr = (const float4*)(x + (size_t)row * D_MODEL);
    float4 v = xr[tid];
    float ss = v.x*v.x + v.y*v.y + v.z*v.z + v.w*v.w;
    #pragma unroll
    for (int off = 32; off; off >>= 1) ss += __shfl_down(ss, off);
    __shared__ float red[4];
    if ((tid & 63) == 0) red[tid >> 6] = ss;
    __syncthreads();
    float tot = red[0] + red[1] + red[2] + red[3];
    float scale = rsqrtf(tot * (1.f / D_MODEL) + 1e-6f);
    float4 gv = ((const float4*)g)[tid];
    short4 o;
    o.x = f2bf(v.x * scale * gv.x);
    o.y = f2bf(v.y * scale * gv.y);
    o.z = f2bf(v.z * scale * gv.z);
    o.w = f2bf(v.w * scale * gv.w);
    *(short4*)(xn_bf + (size_t)row * D_MODEL + tid * 4) = o;
}

// ---------- bf16-in MFMA NT GEMM (verified r11: absmax 0.0156) ----------
template <int BM, int BN, int RESID>
__global__ __launch_bounds__(256) void gemm_bf16_nt(const short* __restrict__ A,
                                                    const short* __restrict__ B,
                                                    const float* __restrict__ resid,
                                                    float* __restrict__ C,
                                                    int M, int N, int K) {
    constexpr int WRm = BM / 2;         // wave rows
    constexpr int WCn = BN / 2;         // wave cols
    constexpr int MI = WRm / 16;
    constexpr int NJ = WCn / 16;
    __shared__ short Asm[BM][40];
    __shared__ short Bsm[BN][40];
    int tid = threadIdx.x;
    int lane = tid & 63, w = tid >> 6;
    int wr = w >> 1, wc = w & 1;
    int bm = blockIdx.y * BM, bn = blockIdx.x * BN;
    int lrow = lane & 15, kg = (lane >> 4) * 8;
    f32x4 acc[MI][NJ];
    #pragma unroll
    for (int i = 0; i < MI; i++)
        #pragma unroll
        for (int j = 0; j < NJ; j++)
            acc[i][j] = (f32x4){0.f, 0.f, 0.f, 0.f};

    for (int k0 = 0; k0 < K; k0 += 32) {
        #pragma unroll
        for (int c = tid; c < BM * 4; c += 256) {
            int row = c >> 2, q = c & 3;
            *(bf16x8*)&Asm[row][q * 8] =
                *(const bf16x8*)(A + (size_t)(bm + row) * K + k0 + q * 8);
        }
        #pragma unroll
        for (int c = tid; c < BN * 4; c += 256) {
            int row = c >> 2, q = c & 3;
            *(bf16x8*)&Bsm[row][q * 8] =
                *(const bf16x8*)(B + (size_t)(bn + row) * K + k0 + q * 8);
        }
        __syncthreads();
        bf16x8 aF[MI], bF[NJ];
        #pragma unroll
        for (int i = 0; i < MI; i++)
            aF[i] = *(bf16x8*)&Asm[wr * WRm + i * 16 + lrow][kg];
        #pragma unroll
        for (int j = 0; j < NJ; j++)
            bF[j] = *(bf16x8*)&Bsm[wc * WCn + j * 16 + lrow][kg];
        #pragma unroll
        for (int i = 0; i < MI; i++)
            #pragma unroll
            for (int j = 0; j < NJ; j++)
                acc[i][j] = __builtin_amdgcn_mfma_f32_16x16x32_bf16(aF[i], bF[j], acc[i][j], 0, 0, 0);
        __syncthreads();
    }
    #pragma unroll
    for (int i = 0; i < MI; i++)
        #pragma unroll
        for (int j = 0; j < NJ; j++)
            #pragma unroll
            for (int r = 0; r < 4; r++) {
                int m = bm + wr * WRm + i * 16 + (lane >> 4) * 4 + r;
                int n = bn + wc * WCn + j * 16 + lrow;
                size_t off = (size_t)m * N + n;
                float v = acc[i][j][r];
                if (RESID) v += resid[off];
                C[off] = v;
            }
}

// ---------------- depthwise causal conv (K=4) + SiLU ----------------
__global__ __launch_bounds__(256) void conv_silu_kernel(const float* __restrict__ xz,
                                                        const float* __restrict__ cw,
                                                        const float* __restrict__ cb,
                                                        float* __restrict__ xc) {
    int idx = blockIdx.x * 256 + threadIdx.x;           // over NTOK*D_INNER
    int d  = idx & (D_INNER - 1);
    int bt = idx >> 11;                                  // b*TLEN + t
    int t  = bt & (TLEN - 1);
    float s = cb[d];
    #pragma unroll
    for (int j = 0; j < 4; j++) {
        int tt = t - 3 + j;
        if (tt >= 0)
            s += cw[d * 4 + j] * xz[(size_t)(bt - 3 + j) * (2 * D_INNER) + d];
    }
    xc[idx] = silu_f(s);
}

// ------------- params = xc @ W_x^T  (N=33), wave-per-n-group -------------
// Block = one token, 4 waves. Wave w covers full K=2048 (64 lanes x 32 elems)
// and iterates n = w, w+4, ..., <=32. xc slice loaded once per wave, reused.
// Per n: 8 coalesced float4 Wx loads + 32 FMA + 6-level shfl_xor reduce.
// 9 independent reduce chains pipeline; ~60 VGPR -> high occupancy.
__global__ __launch_bounds__(256) void params_kernel(const float* __restrict__ xc,
                                                     const float* __restrict__ Wx,
                                                     float* __restrict__ params) {
    int token = blockIdx.x;
    int lane = threadIdx.x & 63;
    int w = threadIdx.x >> 6;
    const float* xr = xc + (size_t)token * D_INNER + lane * 32;
    float xv[32];
    #pragma unroll
    for (int q = 0; q < 8; q++) {
        float4 v = *(const float4*)(xr + q * 4);
        xv[q*4] = v.x; xv[q*4+1] = v.y; xv[q*4+2] = v.z; xv[q*4+3] = v.w;
    }
    #pragma unroll
    for (int j = 0; j < 9; j++) {
        int n = w + j * 4;
        if (n <= 32) {
            const float* wr = Wx + (size_t)n * D_INNER + lane * 32;
            float s = 0.f;
            #pragma unroll
            for (int q = 0; q < 8; q++) {
                float4 wv = *(const float4*)(wr + q * 4);
                s += xv[q*4]*wv.x + xv[q*4+1]*wv.y + xv[q*4+2]*wv.z + xv[q*4+3]*wv.w;
            }
            s += __shfl_xor(s, 32); s += __shfl_xor(s, 16); s += __shfl_xor(s, 8);
            s += __shfl_xor(s, 4);  s += __shfl_xor(s, 2);  s += __shfl_xor(s, 1);
            if (lane == 0)
                params[(size_t)token * 33 + n] = s;
        }
    }
}

// ================= chunked scan, thread-per-d layout (verified r10) =================
__global__ __launch_bounds__(256) void scan_phase1(const float* __restrict__ params,
                                                   const float* __restrict__ xc,
                                                   const float* __restrict__ Wdt,
                                                   const float* __restrict__ bdt,
                                                   const float* __restrict__ Alog,
                                                   float* __restrict__ hloc,
                                                   float* __restrict__ sdbuf) {
    __shared__ float sP[CHL * 36];
    int tid = threadIdx.x;
    int d  = blockIdx.x * 256 + tid;
    int ch = blockIdx.y;
    int b  = blockIdx.z;
    int t0 = ch * CHL;

    const float* pbase = params + ((size_t)b * TLEN + t0) * 33;
    for (int i = tid; i < CHL * 33; i += 256)
        sP[(i / 33) * 36 + (i % 33)] = pbase[i];
    __syncthreads();

    float A[16];
    #pragma unroll
    for (int s = 0; s < 16; s++) A[s] = -__expf(Alog[d * 16 + s]);
    float wdt = Wdt[d], bdtd = bdt[d];

    float h[16];
    #pragma unroll
    for (int s = 0; s < 16; s++) h[s] = 0.f;
    float sumdt = 0.f;

    const float* xcp = xc + ((size_t)b * TLEN + t0) * D_INNER + d;
    for (int i = 0; i < CHL; i++) {
        float ldt = sP[i * 36 + 32];
        float xcv = xcp[(size_t)i * D_INNER];
        float dt  = softplus_f(ldt * wdt + bdtd);
        sumdt += dt;
        float m = dt * xcv;
        float4 B0 = *(const float4*)&sP[i * 36 + 0];
        float4 B1 = *(const float4*)&sP[i * 36 + 4];
        float4 B2 = *(const float4*)&sP[i * 36 + 8];
        float4 B3 = *(const float4*)&sP[i * 36 + 12];
        float Bv[16] = {B0.x,B0.y,B0.z,B0.w, B1.x,B1.y,B1.z,B1.w,
                        B2.x,B2.y,B2.z,B2.w, B3.x,B3.y,B3.z,B3.w};
        #pragma unroll
        for (int s = 0; s < 16; s++) {
            float ab = __expf(dt * A[s]);
            h[s] = ab * h[s] + m * Bv[s];
        }
    }
    size_t base = ((size_t)(b * NCH + ch) * D_INNER + d);
    sdbuf[base] = sumdt;
    float* hp = hloc + base * 16;
    #pragma unroll
    for (int q = 0; q < 4; q++)
        *(float4*)&hp[q * 4] = (float4){h[q*4], h[q*4+1], h[q*4+2], h[q*4+3]};
}

__global__ __launch_bounds__(256) void scan_combine(const float* __restrict__ hloc,
                                                    const float* __restrict__ sdbuf,
                                                    const float* __restrict__ Alog,
                                                    float* __restrict__ hini) {
    int idx = blockIdx.x * 256 + threadIdx.x;   // over B*D_INNER*16
    int s = idx & 15;
    int d = (idx >> 4) & (D_INNER - 1);
    int b = idx >> 15;
    float As = -__expf(Alog[d * 16 + s]);
    float h0 = 0.f;
    for (int ch = 0; ch < NCH; ch++) {
        size_t base = ((size_t)(b * NCH + ch) * D_INNER + d);
        hini[base * 16 + s] = h0;
        float aP = __expf(As * sdbuf[base]);
        h0 = aP * h0 + hloc[base * 16 + s];
    }
}

// S3: re-scan chunk from h_init; emits y as bf16 (feeds GEMM2 A-operand).
__global__ __launch_bounds__(256) void scan_phase3(const float* __restrict__ params,
                                                   const float* __restrict__ xc,
                                                   const float* __restrict__ xz,
                                                   const float* __restrict__ Wdt,
                                                   const float* __restrict__ bdt,
                                                   const float* __restrict__ Alog,
                                                   const float* __restrict__ Dp,
                                                   const float* __restrict__ hini,
                                                   short* __restrict__ y_bf) {
    __shared__ float sP[CHL * 36];
    int tid = threadIdx.x;
    int d  = blockIdx.x * 256 + tid;
    int ch = blockIdx.y;
    int b  = blockIdx.z;
    int t0 = ch * CHL;

    const float* pbase = params + ((size_t)b * TLEN + t0) * 33;
    for (int i = tid; i < CHL * 33; i += 256)
        sP[(i / 33) * 36 + (i % 33)] = pbase[i];
    __syncthreads();

    float A[16];
    #pragma unroll
    for (int s = 0; s < 16; s++) A[s] = -__expf(Alog[d * 16 + s]);
    float wdt = Wdt[d], bdtd = bdt[d], Dd = Dp[d];

    float h[16];
    const float* hp = hini + ((size_t)(b * NCH + ch) * D_INNER + d) * 16;
    #pragma unroll
    for (int q = 0; q < 4; q++) {
        float4 hv = *(const float4*)&hp[q * 4];
        h[q*4] = hv.x; h[q*4+1] = hv.y; h[q*4+2] = hv.z; h[q*4+3] = hv.w;
    }

    const float* xcp = xc + ((size_t)b * TLEN + t0) * D_INNER + d;
    const float* zp  = xz + ((size_t)b * TLEN + t0) * 2 * D_INNER + D_INNER + d;
    short* yp        = y_bf + ((size_t)b * TLEN + t0) * D_INNER + d;
    for (int i = 0; i < CHL; i++) {
        float ldt = sP[i * 36 + 32];
        float xcv = xcp[(size_t)i * D_INNER];
        float zv  = zp[(size_t)i * 2 * D_INNER];
        float dt  = softplus_f(ldt * wdt + bdtd);
        float m = dt * xcv;
        float4 B0 = *(const float4*)&sP[i * 36 + 0];
        float4 B1 = *(const float4*)&sP[i * 36 + 4];
        float4 B2 = *(const float4*)&sP[i * 36 + 8];
        float4 B3 = *(const float4*)&sP[i * 36 + 12];
        float4 C0 = *(const float4*)&sP[i * 36 + 16];
        float4 C1 = *(const float4*)&sP[i * 36 + 20];
        float4 C2 = *(const float4*)&sP[i * 36 + 24];
        float4 C3 = *(const float4*)&sP[i * 36 + 28];
        float Bv[16] = {B0.x,B0.y,B0.z,B0.w, B1.x,B1.y,B1.z,B1.w,
                        B2.x,B2.y,B2.z,B2.w, B3.x,B3.y,B3.z,B3.w};
        float Cv[16] = {C0.x,C0.y,C0.z,C0.w, C1.x,C1.y,C1.z,C1.w,
                        C2.x,C2.y,C2.z,C2.w, C3.x,C3.y,C3.z,C3.w};
        float y = 0.f;
        #pragma unroll
        for (int s = 0; s < 16; s++) {
            float ab = __expf(dt * A[s]);
            h[s] = ab * h[s] + m * Bv[s];
            y += h[s] * Cv[s];
        }
        yp[(size_t)i * D_INNER] = f2bf((y + xcv * Dd) * silu_f(zv));
    }
}

extern "C" void kernel_launch(void* const* d_in, const int* in_sizes, int n_in,
                              void* d_out, int out_size, void* d_ws, size_t ws_size,
                              hipStream_t stream) {
    const float* x      = (const float*)d_in[0];
    const float* g      = (const float*)d_in[1];
    const float* W_in   = (const float*)d_in[2];
    const float* W_out  = (const float*)d_in[3];
    const float* conv_w = (const float*)d_in[4];
    const float* conv_b = (const float*)d_in[5];
    const float* W_x    = (const float*)d_in[6];
    const float* W_dt   = (const float*)d_in[7];
    const float* b_dt   = (const float*)d_in[8];
    const float* A_log  = (const float*)d_in[9];
    const float* Dp     = (const float*)d_in[10];
    float* out = (float*)d_out;

    // workspace layout (84.7 MB total, verified r11):
    float* ws    = (float*)d_ws;
    float* hloc  = ws;                                        // 2,097,152 f
    float* xz    = ws + 2097152;                              // 8,388,608 f
    float* xc    = ws + 10485760;                             // 4,194,304 f
    float* par   = ws + 14680064;                             // 67,584 f
    short* y_bf  = (short*)(ws + 14747648);                   // 4,194,304 s
    short* xn_bf = (short*)(ws + 16844800);                   // 2,097,152 s
    short* wbf_o = (short*)(ws + 17893376);                   // 2,097,152 s (W_out bf16)
    float* hini  = ws + 18941952;                             // 2,097,152 f
    short* wbf_i = (short*)hini;                              // W_in bf16 overlays hini
    float* sd    = ws + 21039104;                             // 131,072 f

    // one-shot weight conversion
    cvt_bf16_kernel<<<(2 * D_INNER * D_MODEL) / (256 * 8), 256, 0, stream>>>(W_in, wbf_i);
    cvt_bf16_kernel<<<(D_MODEL * D_INNER) / (256 * 8), 256, 0, stream>>>(W_out, wbf_o);

    rmsnorm_kernel<<<NTOK, 256, 0, stream>>>(x, g, xn_bf);
    // GEMM1: M=2048, N=4096, K=1024 — 128x128, 512 blocks
    gemm_bf16_nt<128, 128, 0><<<dim3((2 * D_INNER) / 128, NTOK / 128), 256, 0, stream>>>(
        xn_bf, wbf_i, nullptr, xz, NTOK, 2 * D_INNER, D_MODEL);
    conv_silu_kernel<<<(NTOK * D_INNER) / 256, 256, 0, stream>>>(xz, conv_w, conv_b, xc);
    params_kernel<<<NTOK, 256, 0, stream>>>(xc, W_x, par);

    dim3 sgrid(D_INNER / 256, NCH, BATCH);
    scan_phase1<<<sgrid, 256, 0, stream>>>(par, xc, W_dt, b_dt, A_log, hloc, sd);
    scan_combine<<<(BATCH * D_INNER * 16) / 256, 256, 0, stream>>>(hloc, sd, A_log, hini);
    scan_phase3<<<sgrid, 256, 0, stream>>>(par, xc, xz, W_dt, b_dt, A_log, Dp, hini, y_bf);

    // GEMM2: M=2048, N=1024, K=2048 — 64x64, 512 blocks (2 blocks/CU)
    gemm_bf16_nt<64, 64, 1><<<dim3(D_MODEL / 64, NTOK / 64), 256, 0, stream>>>(
        y_bf, wbf_o, x, out, NTOK, D_MODEL, D_INNER);
}

// Round 13
// 268.421 us; speedup vs baseline: 3.4383x; 1.2275x over previous
//
#include <hip/hip_runtime.h>
#include <hip/hip_bf16.h>
#include <math.h>

#define D_MODEL 1024
#define D_STATE 16
#define D_CONV  4
#define D_INNER 2048
#define TLEN    1024
#define BATCH   2
#define NTOK    (BATCH*TLEN)   // 2048
#define NCH     32             // scan chunks
#define CHL     (TLEN/NCH)     // 32 steps per chunk
#define PTOKS   2              // tokens per params block

typedef __attribute__((ext_vector_type(8))) short bf16x8;
typedef __attribute__((ext_vector_type(4))) float f32x4;

__device__ __forceinline__ float silu_f(float v) { return v / (1.f + __expf(-v)); }

__device__ __forceinline__ float softplus_f(float x) {
    return (x > 15.f) ? x : __logf(1.f + __expf(x));
}

// fp32 -> bf16 (RNE), finite inputs
__device__ __forceinline__ short f2bf(float x) {
    unsigned u = __builtin_bit_cast(unsigned, x);
    unsigned r = (u + 0x7FFFu + ((u >> 16) & 1u)) >> 16;
    return (short)r;
}

// ---------------- fp32 -> bf16 bulk convert (weights, once per call) ----------------
__global__ __launch_bounds__(256) void cvt_bf16_kernel(const float* __restrict__ in,
                                                       short* __restrict__ out) {
    int idx = (blockIdx.x * 256 + threadIdx.x) * 8;
    float4 v0 = *(const float4*)(in + idx);
    float4 v1 = *(const float4*)(in + idx + 4);
    bf16x8 pk;
    pk[0] = f2bf(v0.x); pk[1] = f2bf(v0.y); pk[2] = f2bf(v0.z); pk[3] = f2bf(v0.w);
    pk[4] = f2bf(v1.x); pk[5] = f2bf(v1.y); pk[6] = f2bf(v1.z); pk[7] = f2bf(v1.w);
    *(bf16x8*)(out + idx) = pk;
}

// ---------------- RMSNorm: one block per token, emits bf16 ----------------
__global__ __launch_bounds__(256) void rmsnorm_kernel(const float* __restrict__ x,
                                                      const float* __restrict__ g,
                                                      short* __restrict__ xn_bf) {
    int row = blockIdx.x;
    int tid = threadIdx.x;
    const float4* xr = (const float4*)(x + (size_t)row * D_MODEL);
    float4 v = xr[tid];
    float ss = v.x*v.x + v.y*v.y + v.z*v.z + v.w*v.w;
    #pragma unroll
    for (int off = 32; off; off >>= 1) ss += __shfl_down(ss, off);
    __shared__ float red[4];
    if ((tid & 63) == 0) red[tid >> 6] = ss;
    __syncthreads();
    float tot = red[0] + red[1] + red[2] + red[3];
    float scale = rsqrtf(tot * (1.f / D_MODEL) + 1e-6f);
    float4 gv = ((const float4*)g)[tid];
    short4 o;
    o.x = f2bf(v.x * scale * gv.x);
    o.y = f2bf(v.y * scale * gv.y);
    o.z = f2bf(v.z * scale * gv.z);
    o.w = f2bf(v.w * scale * gv.w);
    *(short4*)(xn_bf + (size_t)row * D_MODEL + tid * 4) = o;
}

// ---------- bf16-in MFMA NT GEMM (verified r11: absmax 0.0156) ----------
template <int BM, int BN, int RESID>
__global__ __launch_bounds__(256) void gemm_bf16_nt(const short* __restrict__ A,
                                                    const short* __restrict__ B,
                                                    const float* __restrict__ resid,
                                                    float* __restrict__ C,
                                                    int M, int N, int K) {
    constexpr int WRm = BM / 2;         // wave rows
    constexpr int WCn = BN / 2;         // wave cols
    constexpr int MI = WRm / 16;
    constexpr int NJ = WCn / 16;
    __shared__ short Asm[BM][40];
    __shared__ short Bsm[BN][40];
    int tid = threadIdx.x;
    int lane = tid & 63, w = tid >> 6;
    int wr = w >> 1, wc = w & 1;
    int bm = blockIdx.y * BM, bn = blockIdx.x * BN;
    int lrow = lane & 15, kg = (lane >> 4) * 8;
    f32x4 acc[MI][NJ];
    #pragma unroll
    for (int i = 0; i < MI; i++)
        #pragma unroll
        for (int j = 0; j < NJ; j++)
            acc[i][j] = (f32x4){0.f, 0.f, 0.f, 0.f};

    for (int k0 = 0; k0 < K; k0 += 32) {
        #pragma unroll
        for (int c = tid; c < BM * 4; c += 256) {
            int row = c >> 2, q = c & 3;
            *(bf16x8*)&Asm[row][q * 8] =
                *(const bf16x8*)(A + (size_t)(bm + row) * K + k0 + q * 8);
        }
        #pragma unroll
        for (int c = tid; c < BN * 4; c += 256) {
            int row = c >> 2, q = c & 3;
            *(bf16x8*)&Bsm[row][q * 8] =
                *(const bf16x8*)(B + (size_t)(bn + row) * K + k0 + q * 8);
        }
        __syncthreads();
        bf16x8 aF[MI], bF[NJ];
        #pragma unroll
        for (int i = 0; i < MI; i++)
            aF[i] = *(bf16x8*)&Asm[wr * WRm + i * 16 + lrow][kg];
        #pragma unroll
        for (int j = 0; j < NJ; j++)
            bF[j] = *(bf16x8*)&Bsm[wc * WCn + j * 16 + lrow][kg];
        #pragma unroll
        for (int i = 0; i < MI; i++)
            #pragma unroll
            for (int j = 0; j < NJ; j++)
                acc[i][j] = __builtin_amdgcn_mfma_f32_16x16x32_bf16(aF[i], bF[j], acc[i][j], 0, 0, 0);
        __syncthreads();
    }
    #pragma unroll
    for (int i = 0; i < MI; i++)
        #pragma unroll
        for (int j = 0; j < NJ; j++)
            #pragma unroll
            for (int r = 0; r < 4; r++) {
                int m = bm + wr * WRm + i * 16 + (lane >> 4) * 4 + r;
                int n = bn + wc * WCn + j * 16 + lrow;
                size_t off = (size_t)m * N + n;
                float v = acc[i][j][r];
                if (RESID) v += resid[off];
                C[off] = v;
            }
}

// ---------------- depthwise causal conv (K=4) + SiLU ----------------
__global__ __launch_bounds__(256) void conv_silu_kernel(const float* __restrict__ xz,
                                                        const float* __restrict__ cw,
                                                        const float* __restrict__ cb,
                                                        float* __restrict__ xc) {
    int idx = blockIdx.x * 256 + threadIdx.x;           // over NTOK*D_INNER
    int d  = idx & (D_INNER - 1);
    int bt = idx >> 11;                                  // b*TLEN + t
    int t  = bt & (TLEN - 1);
    float s = cb[d];
    #pragma unroll
    for (int j = 0; j < 4; j++) {
        int tt = t - 3 + j;
        if (tt >= 0)
            s += cw[d * 4 + j] * xz[(size_t)(bt - 3 + j) * (2 * D_INNER) + d];
    }
    xc[idx] = silu_f(s);
}

// ------------- params = xc @ W_x^T  (N=33), coalesced + 2 tokens/block -------------
// Block covers PTOKS tokens, 4 waves. Wave w handles n = w, w+4, ..., <=32 for
// both tokens (W_x row loaded once, reused). Lane reads float4 at
// lane*4 + q*256 — wave-contiguous 1KB per load instruction (fully coalesced).
// Shuffle-reduce is order-independent so any disjoint K-partition works.
__global__ __launch_bounds__(256) void params_kernel(const float* __restrict__ xc,
                                                     const float* __restrict__ Wx,
                                                     float* __restrict__ params) {
    int tok0 = blockIdx.x * PTOKS;
    int lane = threadIdx.x & 63;
    int w = threadIdx.x >> 6;
    float xv[PTOKS][32];
    #pragma unroll
    for (int t = 0; t < PTOKS; t++) {
        const float* xr = xc + (size_t)(tok0 + t) * D_INNER;
        #pragma unroll
        for (int q = 0; q < 8; q++) {
            float4 v = *(const float4*)(xr + lane * 4 + q * 256);
            xv[t][q*4+0] = v.x; xv[t][q*4+1] = v.y;
            xv[t][q*4+2] = v.z; xv[t][q*4+3] = v.w;
        }
    }
    #pragma unroll
    for (int j = 0; j < 9; j++) {
        int n = w + j * 4;
        if (n <= 32) {
            const float* wr = Wx + (size_t)n * D_INNER;
            float s[PTOKS] = {};
            #pragma unroll
            for (int q = 0; q < 8; q++) {
                float4 v = *(const float4*)(wr + lane * 4 + q * 256);
                #pragma unroll
                for (int t = 0; t < PTOKS; t++) {
                    s[t] += xv[t][q*4+0]*v.x + xv[t][q*4+1]*v.y
                          + xv[t][q*4+2]*v.z + xv[t][q*4+3]*v.w;
                }
            }
            #pragma unroll
            for (int t = 0; t < PTOKS; t++) {
                float r = s[t];
                r += __shfl_xor(r, 32); r += __shfl_xor(r, 16); r += __shfl_xor(r, 8);
                r += __shfl_xor(r, 4);  r += __shfl_xor(r, 2);  r += __shfl_xor(r, 1);
                if (lane == 0)
                    params[(size_t)(tok0 + t) * 33 + n] = r;
            }
        }
    }
}

// ================= chunked scan, thread-per-d layout (verified r10) =================
__global__ __launch_bounds__(256) void scan_phase1(const float* __restrict__ params,
                                                   const float* __restrict__ xc,
                                                   const float* __restrict__ Wdt,
                                                   const float* __restrict__ bdt,
                                                   const float* __restrict__ Alog,
                                                   float* __restrict__ hloc,
                                                   float* __restrict__ sdbuf) {
    __shared__ float sP[CHL * 36];
    int tid = threadIdx.x;
    int d  = blockIdx.x * 256 + tid;
    int ch = blockIdx.y;
    int b  = blockIdx.z;
    int t0 = ch * CHL;

    const float* pbase = params + ((size_t)b * TLEN + t0) * 33;
    for (int i = tid; i < CHL * 33; i += 256)
        sP[(i / 33) * 36 + (i % 33)] = pbase[i];
    __syncthreads();

    float A[16];
    #pragma unroll
    for (int s = 0; s < 16; s++) A[s] = -__expf(Alog[d * 16 + s]);
    float wdt = Wdt[d], bdtd = bdt[d];

    float h[16];
    #pragma unroll
    for (int s = 0; s < 16; s++) h[s] = 0.f;
    float sumdt = 0.f;

    const float* xcp = xc + ((size_t)b * TLEN + t0) * D_INNER + d;
    for (int i = 0; i < CHL; i++) {
        float ldt = sP[i * 36 + 32];
        float xcv = xcp[(size_t)i * D_INNER];
        float dt  = softplus_f(ldt * wdt + bdtd);
        sumdt += dt;
        float m = dt * xcv;
        float4 B0 = *(const float4*)&sP[i * 36 + 0];
        float4 B1 = *(const float4*)&sP[i * 36 + 4];
        float4 B2 = *(const float4*)&sP[i * 36 + 8];
        float4 B3 = *(const float4*)&sP[i * 36 + 12];
        float Bv[16] = {B0.x,B0.y,B0.z,B0.w, B1.x,B1.y,B1.z,B1.w,
                        B2.x,B2.y,B2.z,B2.w, B3.x,B3.y,B3.z,B3.w};
        #pragma unroll
        for (int s = 0; s < 16; s++) {
            float ab = __expf(dt * A[s]);
            h[s] = ab * h[s] + m * Bv[s];
        }
    }
    size_t base = ((size_t)(b * NCH + ch) * D_INNER + d);
    sdbuf[base] = sumdt;
    float* hp = hloc + base * 16;
    #pragma unroll
    for (int q = 0; q < 4; q++)
        *(float4*)&hp[q * 4] = (float4){h[q*4], h[q*4+1], h[q*4+2], h[q*4+3]};
}

__global__ __launch_bounds__(256) void scan_combine(const float* __restrict__ hloc,
                                                    const float* __restrict__ sdbuf,
                                                    const float* __restrict__ Alog,
                                                    float* __restrict__ hini) {
    int idx = blockIdx.x * 256 + threadIdx.x;   // over B*D_INNER*16
    int s = idx & 15;
    int d = (idx >> 4) & (D_INNER - 1);
    int b = idx >> 15;
    float As = -__expf(Alog[d * 16 + s]);
    float h0 = 0.f;
    for (int ch = 0; ch < NCH; ch++) {
        size_t base = ((size_t)(b * NCH + ch) * D_INNER + d);
        hini[base * 16 + s] = h0;
        float aP = __expf(As * sdbuf[base]);
        h0 = aP * h0 + hloc[base * 16 + s];
    }
}

// S3: re-scan chunk from h_init; emits y as bf16 (feeds GEMM2 A-operand).
__global__ __launch_bounds__(256) void scan_phase3(const float* __restrict__ params,
                                                   const float* __restrict__ xc,
                                                   const float* __restrict__ xz,
                                                   const float* __restrict__ Wdt,
                                                   const float* __restrict__ bdt,
                                                   const float* __restrict__ Alog,
                                                   const float* __restrict__ Dp,
                                                   const float* __restrict__ hini,
                                                   short* __restrict__ y_bf) {
    __shared__ float sP[CHL * 36];
    int tid = threadIdx.x;
    int d  = blockIdx.x * 256 + tid;
    int ch = blockIdx.y;
    int b  = blockIdx.z;
    int t0 = ch * CHL;

    const float* pbase = params + ((size_t)b * TLEN + t0) * 33;
    for (int i = tid; i < CHL * 33; i += 256)
        sP[(i / 33) * 36 + (i % 33)] = pbase[i];
    __syncthreads();

    float A[16];
    #pragma unroll
    for (int s = 0; s < 16; s++) A[s] = -__expf(Alog[d * 16 + s]);
    float wdt = Wdt[d], bdtd = bdt[d], Dd = Dp[d];

    float h[16];
    const float* hp = hini + ((size_t)(b * NCH + ch) * D_INNER + d) * 16;
    #pragma unroll
    for (int q = 0; q < 4; q++) {
        float4 hv = *(const float4*)&hp[q * 4];
        h[q*4] = hv.x; h[q*4+1] = hv.y; h[q*4+2] = hv.z; h[q*4+3] = hv.w;
    }

    const float* xcp = xc + ((size_t)b * TLEN + t0) * D_INNER + d;
    const float* zp  = xz + ((size_t)b * TLEN + t0) * 2 * D_INNER + D_INNER + d;
    short* yp        = y_bf + ((size_t)b * TLEN + t0) * D_INNER + d;
    for (int i = 0; i < CHL; i++) {
        float ldt = sP[i * 36 + 32];
        float xcv = xcp[(size_t)i * D_INNER];
        float zv  = zp[(size_t)i * 2 * D_INNER];
        float dt  = softplus_f(ldt * wdt + bdtd);
        float m = dt * xcv;
        float4 B0 = *(const float4*)&sP[i * 36 + 0];
        float4 B1 = *(const float4*)&sP[i * 36 + 4];
        float4 B2 = *(const float4*)&sP[i * 36 + 8];
        float4 B3 = *(const float4*)&sP[i * 36 + 12];
        float4 C0 = *(const float4*)&sP[i * 36 + 16];
        float4 C1 = *(const float4*)&sP[i * 36 + 20];
        float4 C2 = *(const float4*)&sP[i * 36 + 24];
        float4 C3 = *(const float4*)&sP[i * 36 + 28];
        float Bv[16] = {B0.x,B0.y,B0.z,B0.w, B1.x,B1.y,B1.z,B1.w,
                        B2.x,B2.y,B2.z,B2.w, B3.x,B3.y,B3.z,B3.w};
        float Cv[16] = {C0.x,C0.y,C0.z,C0.w, C1.x,C1.y,C1.z,C1.w,
                        C2.x,C2.y,C2.z,C2.w, C3.x,C3.y,C3.z,C3.w};
        float y = 0.f;
        #pragma unroll
        for (int s = 0; s < 16; s++) {
            float ab = __expf(dt * A[s]);
            h[s] = ab * h[s] + m * Bv[s];
            y += h[s] * Cv[s];
        }
        yp[(size_t)i * D_INNER] = f2bf((y + xcv * Dd) * silu_f(zv));
    }
}

extern "C" void kernel_launch(void* const* d_in, const int* in_sizes, int n_in,
                              void* d_out, int out_size, void* d_ws, size_t ws_size,
                              hipStream_t stream) {
    const float* x      = (const float*)d_in[0];
    const float* g      = (const float*)d_in[1];
    const float* W_in   = (const float*)d_in[2];
    const float* W_out  = (const float*)d_in[3];
    const float* conv_w = (const float*)d_in[4];
    const float* conv_b = (const float*)d_in[5];
    const float* W_x    = (const float*)d_in[6];
    const float* W_dt   = (const float*)d_in[7];
    const float* b_dt   = (const float*)d_in[8];
    const float* A_log  = (const float*)d_in[9];
    const float* Dp     = (const float*)d_in[10];
    float* out = (float*)d_out;

    // workspace layout (84.7 MB total, verified r11):
    float* ws    = (float*)d_ws;
    float* hloc  = ws;                                        // 2,097,152 f
    float* xz    = ws + 2097152;                              // 8,388,608 f
    float* xc    = ws + 10485760;                             // 4,194,304 f
    float* par   = ws + 14680064;                             // 67,584 f
    short* y_bf  = (short*)(ws + 14747648);                   // 4,194,304 s
    short* xn_bf = (short*)(ws + 16844800);                   // 2,097,152 s
    short* wbf_o = (short*)(ws + 17893376);                   // 2,097,152 s (W_out bf16)
    float* hini  = ws + 18941952;                             // 2,097,152 f
    short* wbf_i = (short*)hini;                              // W_in bf16 overlays hini
    float* sd    = ws + 21039104;                             // 131,072 f

    // one-shot weight conversion
    cvt_bf16_kernel<<<(2 * D_INNER * D_MODEL) / (256 * 8), 256, 0, stream>>>(W_in, wbf_i);
    cvt_bf16_kernel<<<(D_MODEL * D_INNER) / (256 * 8), 256, 0, stream>>>(W_out, wbf_o);

    rmsnorm_kernel<<<NTOK, 256, 0, stream>>>(x, g, xn_bf);
    // GEMM1: M=2048, N=4096, K=1024 — 128x128, 512 blocks
    gemm_bf16_nt<128, 128, 0><<<dim3((2 * D_INNER) / 128, NTOK / 128), 256, 0, stream>>>(
        xn_bf, wbf_i, nullptr, xz, NTOK, 2 * D_INNER, D_MODEL);
    conv_silu_kernel<<<(NTOK * D_INNER) / 256, 256, 0, stream>>>(xz, conv_w, conv_b, xc);
    params_kernel<<<NTOK / PTOKS, 256, 0, stream>>>(xc, W_x, par);

    dim3 sgrid(D_INNER / 256, NCH, BATCH);
    scan_phase1<<<sgrid, 256, 0, stream>>>(par, xc, W_dt, b_dt, A_log, hloc, sd);
    scan_combine<<<(BATCH * D_INNER * 16) / 256, 256, 0, stream>>>(hloc, sd, A_log, hini);
    scan_phase3<<<sgrid, 256, 0, stream>>>(par, xc, xz, W_dt, b_dt, A_log, Dp, hini, y_bf);

    // GEMM2: M=2048, N=1024, K=2048 — 64x64, 512 blocks (2 blocks/CU)
    gemm_bf16_nt<64, 64, 1><<<dim3(D_MODEL / 64, NTOK / 64), 256, 0, stream>>>(
        y_bf, wbf_o, x, out, NTOK, D_MODEL, D_INNER);
}